// Round 9
// baseline (2506.023 us; speedup 1.0000x reference)
//
#include <hip/hip_runtime.h>
#include <hip/hip_cooperative_groups.h>
#include <math.h>

namespace cg = cooperative_groups;

#define S_ 257
#define D_ 512
#define MB_ 5    // ceil(257/64)
#define GRID_ 256
#define NT_ 512  // 8 waves/block = 2 waves/SIMD at 1 block/CU

struct MegaP {
  const float* in_x;
  const float* emb_w;
  const float* emb_b;
  const float* pos_emb;
  const float* cls_emb;
  const float* ipw;
  const float* ipb;
  const float* aow;
  const float* aob;
  const float* fw1;
  const float* fb1;
  const float* fw2;
  const float* fb2;
  const float* ln1g;
  const float* ln1b;
  const float* ln2g;
  const float* ln2b;
  const float* out_w;
  const float* out_b;
  float* ws;
};

using Tile = float[2][32][68];

// ---- embed row job (uniform barrier structure incl. row 0) -----------------
__device__ __forceinline__ void embed_job(int row, bool active, int tid,
                                          const MegaP& p, float* sbuf) {
  float* src = p.ws;
  if (active && row > 0 && tid < 64) sbuf[tid] = p.in_x[(row - 1) * 64 + tid];
  __syncthreads();
  if (active) {
    for (int j = tid; j < D_; j += 256) {
      float v;
      if (row == 0) {
        v = p.cls_emb[j] + p.pos_emb[j];
      } else {
        float acc = p.emb_b[j];
#pragma unroll 8
        for (int k = 0; k < 64; ++k) acc += sbuf[k] * p.emb_w[k * D_ + j];
        v = acc + p.pos_emb[row * D_ + j];
      }
      src[row * D_ + j] = v;
    }
  }
  __syncthreads();
}

// ---- proven 64x64 dbuf split-K GEMM, per 256-thread sub-block --------------
template <bool TRANSB>
__device__ __forceinline__ void gemm_job(int job, bool active, int tid,
                                         const float* __restrict__ A,
                                         const float* __restrict__ B,
                                         float* __restrict__ out, int M, int N,
                                         int K, int kslice, int nb, int MNtot,
                                         Tile& As, Tile& Bs) {
  const int by = job % MB_;
  const int t2 = job / MB_;
  const int bx = t2 % nb;
  const int bz = t2 / nb;
  const int m0 = by * 64, n0 = bx * 64, kbeg = bz * kslice;

  const int sm = tid & 63;
  const int sk = (tid >> 6) * 8;
  const int bk = tid >> 3;
  const int bn = (tid & 7) * 8;

  float4 ra0, ra1, rb0, rb1;
  const float4 z4 = make_float4(0.f, 0.f, 0.f, 0.f);

  auto loadT = [&](int k0) {
    const int gm = m0 + sm;
    if (gm < M) {
      const float* ptr = &A[(size_t)gm * K + k0 + sk];
      ra0 = *reinterpret_cast<const float4*>(ptr);
      ra1 = *reinterpret_cast<const float4*>(ptr + 4);
    } else {
      ra0 = z4;
      ra1 = z4;
    }
    if (TRANSB) {
      const float* ptr = &B[(size_t)(n0 + sm) * K + k0 + sk];
      rb0 = *reinterpret_cast<const float4*>(ptr);
      rb1 = *reinterpret_cast<const float4*>(ptr + 4);
    } else {
      const float* ptr = &B[(size_t)(k0 + bk) * N + n0 + bn];
      rb0 = *reinterpret_cast<const float4*>(ptr);
      rb1 = *reinterpret_cast<const float4*>(ptr + 4);
    }
  };
  auto storeT = [&](int b) {
    As[b][sk + 0][sm] = ra0.x;
    As[b][sk + 1][sm] = ra0.y;
    As[b][sk + 2][sm] = ra0.z;
    As[b][sk + 3][sm] = ra0.w;
    As[b][sk + 4][sm] = ra1.x;
    As[b][sk + 5][sm] = ra1.y;
    As[b][sk + 6][sm] = ra1.z;
    As[b][sk + 7][sm] = ra1.w;
    if (TRANSB) {
      Bs[b][sk + 0][sm] = rb0.x;
      Bs[b][sk + 1][sm] = rb0.y;
      Bs[b][sk + 2][sm] = rb0.z;
      Bs[b][sk + 3][sm] = rb0.w;
      Bs[b][sk + 4][sm] = rb1.x;
      Bs[b][sk + 5][sm] = rb1.y;
      Bs[b][sk + 6][sm] = rb1.z;
      Bs[b][sk + 7][sm] = rb1.w;
    } else {
      *reinterpret_cast<float4*>(&Bs[b][bk][bn]) = rb0;
      *reinterpret_cast<float4*>(&Bs[b][bk][bn + 4]) = rb1;
    }
  };

  float acc[4][4] = {};
  const int tx4 = (tid & 15) * 4;
  const int ty4 = (tid >> 4) * 4;

  const int nt = kslice >> 5;
  loadT(kbeg);
  storeT(0);
  __syncthreads();
  int buf = 0;
  for (int t = 0; t < nt; ++t) {
    const bool more = (t + 1 < nt);
    if (more) loadT(kbeg + (t + 1) * 32);
#pragma unroll
    for (int k = 0; k < 32; ++k) {
      const float4 av = *reinterpret_cast<const float4*>(&As[buf][k][ty4]);
      const float4 bv = *reinterpret_cast<const float4*>(&Bs[buf][k][tx4]);
      acc[0][0] += av.x * bv.x;
      acc[0][1] += av.x * bv.y;
      acc[0][2] += av.x * bv.z;
      acc[0][3] += av.x * bv.w;
      acc[1][0] += av.y * bv.x;
      acc[1][1] += av.y * bv.y;
      acc[1][2] += av.y * bv.z;
      acc[1][3] += av.y * bv.w;
      acc[2][0] += av.z * bv.x;
      acc[2][1] += av.z * bv.y;
      acc[2][2] += av.z * bv.z;
      acc[2][3] += av.z * bv.w;
      acc[3][0] += av.w * bv.x;
      acc[3][1] += av.w * bv.y;
      acc[3][2] += av.w * bv.z;
      acc[3][3] += av.w * bv.w;
    }
    if (more) storeT(buf ^ 1);
    __syncthreads();
    buf ^= 1;
  }

  if (active) {
    float* pb = out + (size_t)bz * MNtot;
#pragma unroll
    for (int i = 0; i < 4; ++i) {
      const int m = m0 + ty4 + i;
      if (m >= M) break;
      *reinterpret_cast<float4*>(&pb[(size_t)m * N + n0 + tx4]) =
          make_float4(acc[i][0], acc[i][1], acc[i][2], acc[i][3]);
    }
  }
  __syncthreads();
}

// ---- attention job (one query row per 256-thread sub-block) ----------------
__device__ __forceinline__ void attn_job(int q, bool active, int tid,
                                         const float* __restrict__ qkv,
                                         float* __restrict__ attnO,
                                         float (*sc)[260], float (*qsh)[64]) {
  const int lane = tid & 31;
  const int hg = tid >> 5;
  {
    const int e = tid * 2;
    const float2 v =
        *reinterpret_cast<const float2*>(&qkv[(size_t)q * 1536 + e]);
    qsh[e >> 6][e & 63] = v.x;
    qsh[e >> 6][(e & 63) + 1] = v.y;
  }
  __syncthreads();
  float lm = -1e30f;
  for (int j = lane; j < S_; j += 32) {
    const float4* kr =
        reinterpret_cast<const float4*>(&qkv[(size_t)j * 1536 + 512 + hg * 64]);
    const float4* qr = reinterpret_cast<const float4*>(&qsh[hg][0]);
    float acc = 0.f;
#pragma unroll
    for (int d = 0; d < 16; ++d) {
      const float4 kk = kr[d], qq = qr[d];
      acc += kk.x * qq.x + kk.y * qq.y + kk.z * qq.z + kk.w * qq.w;
    }
    const float s = acc * 0.125f;
    sc[hg][j] = s;
    lm = fmaxf(lm, s);
  }
#pragma unroll
  for (int off = 16; off > 0; off >>= 1)
    lm = fmaxf(lm, __shfl_xor(lm, off, 32));
  float ls = 0.f;
  for (int j = lane; j < S_; j += 32) {
    const float pw = __expf(sc[hg][j] - lm);
    sc[hg][j] = pw;
    ls += pw;
  }
#pragma unroll
  for (int off = 16; off > 0; off >>= 1) ls += __shfl_xor(ls, off, 32);
  const float inv = 1.f / ls;
  __syncthreads();
  float a0 = 0.f, a1 = 0.f;
#pragma unroll 4
  for (int j = 0; j < S_; ++j) {
    const float pw = sc[hg][j];
    const float2 vv = *reinterpret_cast<const float2*>(
        &qkv[(size_t)j * 1536 + 1024 + hg * 64 + lane * 2]);
    a0 += pw * vv.x;
    a1 += pw * vv.y;
  }
  if (active)
    *reinterpret_cast<float2*>(&attnO[(size_t)q * D_ + hg * 64 + lane * 2]) =
        make_float2(a0 * inv, a1 * inv);
  __syncthreads();
}

// ---- split-K reduce + bias + residual + LayerNorm row job ------------------
__device__ __forceinline__ void ln_job(int row, bool active, int tid,
                                       const float* __restrict__ part, int S,
                                       const float* __restrict__ bias,
                                       float* __restrict__ io,
                                       const float* __restrict__ gg,
                                       const float* __restrict__ bb,
                                       float* redA, float* redB) {
  const size_t base = (size_t)row * D_;
  float x0 = io[base + tid] + bias[tid];
  float x1 = io[base + 256 + tid] + bias[256 + tid];
  for (int s = 0; s < S; ++s) {
    x0 += part[(size_t)s * (size_t)(S_ * D_) + base + tid];
    x1 += part[(size_t)s * (size_t)(S_ * D_) + base + 256 + tid];
  }
  float sm = x0 + x1;
#pragma unroll
  for (int off = 32; off > 0; off >>= 1) sm += __shfl_down(sm, off);
  if ((tid & 63) == 0) redA[tid >> 6] = sm;
  __syncthreads();
  const float mu = (redA[0] + redA[1] + redA[2] + redA[3]) * (1.f / 512.f);
  const float d0 = x0 - mu, d1 = x1 - mu;
  float qv = d0 * d0 + d1 * d1;
#pragma unroll
  for (int off = 32; off > 0; off >>= 1) qv += __shfl_down(qv, off);
  if ((tid & 63) == 0) redB[tid >> 6] = qv;
  __syncthreads();
  const float var = (redB[0] + redB[1] + redB[2] + redB[3]) * (1.f / 512.f);
  const float inv = rsqrtf(var + 1e-5f);
  if (active) {
    io[base + tid] = d0 * inv * gg[tid] + bb[tid];
    io[base + 256 + tid] = d1 * inv * gg[256 + tid] + bb[256 + tid];
  }
  __syncthreads();
}

// ---- head gemv job ---------------------------------------------------------
__device__ __forceinline__ void gemv_job(int job, int tid,
                                         const float* __restrict__ src,
                                         const float* __restrict__ out_w,
                                         float* __restrict__ part,
                                         float* __restrict__ sbuf) {
  const int jc = job & 63;
  const int dc = job >> 6;
  if (tid < 64) sbuf[tid] = src[dc * 64 + tid];
  __syncthreads();
  const int j0 = jc * 1024 + tid * 4;
  float4 acc = make_float4(0.f, 0.f, 0.f, 0.f);
  for (int d = 0; d < 64; ++d) {
    const float sv = sbuf[d];
    const float4 w = *reinterpret_cast<const float4*>(
        &out_w[(size_t)(dc * 64 + d) * 65536 + j0]);
    acc.x += sv * w.x;
    acc.y += sv * w.y;
    acc.z += sv * w.z;
    acc.w += sv * w.w;
  }
  *reinterpret_cast<float4*>(&part[(size_t)dc * 65536 + j0]) = acc;
  __syncthreads();
}

// ---- barrier-free grid-stride reduce (+bias, opt relu) ---------------------
__device__ __forceinline__ void reduce_phase(int bid, int tid512,
                                             const float* __restrict__ part,
                                             const float* __restrict__ bias,
                                             float* __restrict__ out, int MN4,
                                             int N4, int S, int relu) {
  for (int i = bid * NT_ + tid512; i < MN4; i += GRID_ * NT_) {
    float4 acc = reinterpret_cast<const float4*>(bias)[i % N4];
    for (int s = 0; s < S; ++s) {
      const float4 v =
          reinterpret_cast<const float4*>(part)[(size_t)s * MN4 + i];
      acc.x += v.x;
      acc.y += v.y;
      acc.z += v.z;
      acc.w += v.w;
    }
    if (relu) {
      acc.x = fmaxf(acc.x, 0.f);
      acc.y = fmaxf(acc.y, 0.f);
      acc.z = fmaxf(acc.z, 0.f);
      acc.w = fmaxf(acc.w, 0.f);
    }
    reinterpret_cast<float4*>(out)[i] = acc;
  }
}

// ---- one phase of the pipeline (shared by mega and fallback wrapper) -------
__device__ void run_phase(int phase, int l, const MegaP& p, int bid, int g,
                          int tid, int tid512, Tile& As, Tile& Bs,
                          float (*sc)[260], float (*qsh)[64], float* redA,
                          float* redB, float* sbuf) {
  float* ws = p.ws;
  float* src = ws;               // 257*512
  float* qkv = ws + 131584;      // 257*1536
  float* attnO = ws + 526336;    // 257*512
  float* ffh = ws + 657920;      // 257*2048
  float* logits = ws + 1184256;  // 65536
  float* part = ws + 1249792;    // up to 4*394752
  const int jr = bid * 2 + g;    // sub-block job slot (uniform per sub-block)
  switch (phase) {
    case 0: {
      const bool a = jr < S_;
      embed_job(a ? jr : S_ - 1, a, tid, p, sbuf);
    } break;
    case 1: {  // qkv partials: splitK4, 480 jobs, nt=4
      const bool a = jr < 480;
      gemm_job<true>(a ? jr : 479, a, tid, src,
                     p.ipw + (size_t)l * 1536 * 512, part, S_, 1536, 512, 128,
                     24, S_ * 1536, As, Bs);
    } break;
    case 2:  // qkv reduce + bias
      reduce_phase(bid, tid512, part, p.ipb + l * 1536, qkv, (S_ * 1536) / 4,
                   384, 4, 0);
      break;
    case 3: {
      const bool a = jr < S_;
      attn_job(a ? jr : S_ - 1, a, tid, qkv, attnO, sc, qsh);
    } break;
    case 4: {  // proj partials: splitK8, 320 jobs, nt=2
      const bool a = jr < 320;
      gemm_job<true>(a ? jr : 319, a, tid, attnO,
                     p.aow + (size_t)l * 512 * 512, part, S_, 512, 512, 64, 8,
                     S_ * D_, As, Bs);
    } break;
    case 5: {
      const bool a = jr < S_;
      ln_job(a ? jr : S_ - 1, a, tid, part, 8, p.aob + l * 512, src,
             p.ln1g + l * 512, p.ln1b + l * 512, redA, redB);
    } break;
    case 6: {  // ff1 partials: splitK2, 320 jobs, nt=8
      const bool a = jr < 320;
      gemm_job<false>(a ? jr : 319, a, tid, src,
                      p.fw1 + (size_t)l * 512 * 2048, part, S_, 2048, 512, 256,
                      32, S_ * 2048, As, Bs);
    } break;
    case 7:  // ff1 reduce + bias + relu
      reduce_phase(bid, tid512, part, p.fb1 + l * 2048, ffh, (S_ * 2048) / 4,
                   512, 2, 1);
      break;
    case 8: {  // ff2 partials: splitK8, 320 jobs, nt=8
      const bool a = jr < 320;
      gemm_job<false>(a ? jr : 319, a, tid, ffh,
                      p.fw2 + (size_t)l * 2048 * 512, part, S_, 512, 2048, 256,
                      8, S_ * D_, As, Bs);
    } break;
    case 9: {
      const bool a = jr < S_;
      ln_job(a ? jr : S_ - 1, a, tid, part, 8, p.fb2 + l * 512, src,
             p.ln2g + l * 512, p.ln2b + l * 512, redA, redB);
    } break;
    case 10:  // head gemv: 512 jobs
      gemv_job(jr, tid, src, p.out_w, part, sbuf);
      break;
    case 11:  // logits = sum(8 parts) + out_b
      reduce_phase(bid, tid512, part, p.out_b, logits, 16384, 16384, 8, 0);
      break;
  }
}

// ---- the megakernel: 512 threads = two 256-thread sub-blocks ---------------
__global__ __launch_bounds__(NT_, 2) void mega(MegaP p) {
  cg::grid_group grid = cg::this_grid();
  const int bid = blockIdx.x;
  const int tid512 = threadIdx.x;
  const int g = tid512 >> 8;
  const int tid = tid512 & 255;

  __shared__ __align__(16) float As[2][2][32][68];
  __shared__ __align__(16) float Bs[2][2][32][68];
  __shared__ __align__(16) float sc[2][8][260];
  __shared__ __align__(16) float qsh[2][8][64];
  __shared__ float redA[2][4], redB[2][4];
  __shared__ __align__(16) float sbuf[2][64];

  run_phase(0, 0, p, bid, g, tid, tid512, As[g], Bs[g], sc[g], qsh[g], redA[g],
            redB[g], sbuf[g]);
  grid.sync();
  for (int l = 0; l < 4; ++l) {
    for (int ph = 1; ph <= 9; ++ph) {
      run_phase(ph, l, p, bid, g, tid, tid512, As[g], Bs[g], sc[g], qsh[g],
                redA[g], redB[g], sbuf[g]);
      grid.sync();
    }
  }
  run_phase(10, 0, p, bid, g, tid, tid512, As[g], Bs[g], sc[g], qsh[g],
            redA[g], redB[g], sbuf[g]);
  grid.sync();
  run_phase(11, 0, p, bid, g, tid, tid512, As[g], Bs[g], sc[g], qsh[g],
            redA[g], redB[g], sbuf[g]);
}

// ---- fallback: one phase per launch, same code path ------------------------
__global__ __launch_bounds__(NT_, 2) void phase_wrap(MegaP p, int phase,
                                                     int l) {
  const int bid = blockIdx.x;
  const int tid512 = threadIdx.x;
  const int g = tid512 >> 8;
  const int tid = tid512 & 255;
  __shared__ __align__(16) float As[2][2][32][68];
  __shared__ __align__(16) float Bs[2][2][32][68];
  __shared__ __align__(16) float sc[2][8][260];
  __shared__ __align__(16) float qsh[2][8][64];
  __shared__ float redA[2][4], redB[2][4];
  __shared__ __align__(16) float sbuf[2][64];
  run_phase(phase, l, p, bid, g, tid, tid512, As[g], Bs[g], sc[g], qsh[g],
            redA[g], redB[g], sbuf[g]);
}

// ---------------- sinkhorn (rank-1 reformulation, unchanged) ----------------
__global__ __launch_bounds__(1024) void sinkhorn_kernel(
    const float* __restrict__ logits, float* __restrict__ out) {
  const int tid = threadIdx.x;
  const int tx = tid & 31;
  const int ty = tid >> 5;
  const int i0 = ty * 8, j0 = tx * 8;
  float E[8][8];
#pragma unroll
  for (int ii = 0; ii < 8; ++ii) {
    const float4 a =
        *reinterpret_cast<const float4*>(&logits[(i0 + ii) * 256 + j0]);
    const float4 b =
        *reinterpret_cast<const float4*>(&logits[(i0 + ii) * 256 + j0 + 4]);
    E[ii][0] = __expf(a.x);
    E[ii][1] = __expf(a.y);
    E[ii][2] = __expf(a.z);
    E[ii][3] = __expf(a.w);
    E[ii][4] = __expf(b.x);
    E[ii][5] = __expf(b.y);
    E[ii][6] = __expf(b.z);
    E[ii][7] = __expf(b.w);
  }
  __shared__ float part[32][8][32];
  __shared__ int partI[32][8][32];
  __shared__ float uu[256];
  __shared__ float vv[256];
  __shared__ int amax[256];
  if (tid < 256) uu[tid] = 1.f;
  __syncthreads();
  for (int it = 0; it < 20; ++it) {
    float ul[8];
#pragma unroll
    for (int ii = 0; ii < 8; ++ii) ul[ii] = uu[i0 + ii];
#pragma unroll
    for (int jj = 0; jj < 8; ++jj) {
      float s = 0.f;
#pragma unroll
      for (int ii = 0; ii < 8; ++ii) s += E[ii][jj] * ul[ii];
      part[ty][jj][tx] = s;
    }
    __syncthreads();
    if (tid < 256) {
      const int jj = tid >> 5, txr = tid & 31;
      float s = 0.f;
#pragma unroll
      for (int pp = 0; pp < 32; ++pp) s += part[pp][jj][txr];
      vv[txr * 8 + jj] = 1.f / s;
    }
    __syncthreads();
    float vl[8];
#pragma unroll
    for (int jj = 0; jj < 8; ++jj) vl[jj] = vv[j0 + jj];
#pragma unroll
    for (int ii = 0; ii < 8; ++ii) {
      float s = 0.f;
#pragma unroll
      for (int jj = 0; jj < 8; ++jj) s += E[ii][jj] * vl[jj];
      part[ty][ii][tx] = s;
    }
    __syncthreads();
    if (tid < 256) {
      const int i = tid;
      float s = 0.f;
#pragma unroll
      for (int pp = 0; pp < 32; ++pp) {
        const int pr = (pp + i) & 31;
        s += part[i >> 3][i & 7][pr];
      }
      uu[i] = 1.f / s;
    }
    __syncthreads();
  }
  float ul[8], vl[8];
#pragma unroll
  for (int ii = 0; ii < 8; ++ii) ul[ii] = uu[i0 + ii];
#pragma unroll
  for (int jj = 0; jj < 8; ++jj) vl[jj] = vv[j0 + jj];
#pragma unroll
  for (int ii = 0; ii < 8; ++ii) {
    float vals[8];
    float best = -1.f;
    int bidx = 0;
#pragma unroll
    for (int jj = 0; jj < 8; ++jj) {
      const float pv = E[ii][jj] * ul[ii] * vl[jj];
      vals[jj] = pv;
      if (pv > best) {
        best = pv;
        bidx = j0 + jj;
      }
    }
    *reinterpret_cast<float4*>(&out[(i0 + ii) * 256 + j0]) =
        make_float4(vals[0], vals[1], vals[2], vals[3]);
    *reinterpret_cast<float4*>(&out[(i0 + ii) * 256 + j0 + 4]) =
        make_float4(vals[4], vals[5], vals[6], vals[7]);
    part[ty][ii][tx] = best;
    partI[ty][ii][tx] = bidx;
  }
  __syncthreads();
  if (tid < 256) {
    const int i = tid;
    float best = -1.f;
    int bidx = 1 << 30;
#pragma unroll
    for (int pp = 0; pp < 32; ++pp) {
      const int pr = (pp + i) & 31;
      const float v = part[i >> 3][i & 7][pr];
      const int ix = partI[i >> 3][i & 7][pr];
      if (v > best || (v == best && ix < bidx)) {
        best = v;
        bidx = ix;
      }
    }
    amax[i] = bidx;
  }
  __syncthreads();
#pragma unroll
  for (int ii = 0; ii < 8; ++ii) {
    const int am = amax[i0 + ii];
    float4 h0, h1;
    h0.x = (j0 + 0 == am) ? 1.f : 0.f;
    h0.y = (j0 + 1 == am) ? 1.f : 0.f;
    h0.z = (j0 + 2 == am) ? 1.f : 0.f;
    h0.w = (j0 + 3 == am) ? 1.f : 0.f;
    h1.x = (j0 + 4 == am) ? 1.f : 0.f;
    h1.y = (j0 + 5 == am) ? 1.f : 0.f;
    h1.z = (j0 + 6 == am) ? 1.f : 0.f;
    h1.w = (j0 + 7 == am) ? 1.f : 0.f;
    *reinterpret_cast<float4*>(&out[65536 + (i0 + ii) * 256 + j0]) = h0;
    *reinterpret_cast<float4*>(&out[65536 + (i0 + ii) * 256 + j0 + 4]) = h1;
  }
}

// ---------------- host-side launch ------------------------------------------
extern "C" void kernel_launch(void* const* d_in, const int* in_sizes, int n_in,
                              void* d_out, int out_size, void* d_ws,
                              size_t ws_size, hipStream_t stream) {
  (void)in_sizes;
  (void)n_in;
  (void)out_size;
  (void)ws_size;
  MegaP p;
  p.in_x = (const float*)d_in[0];
  p.emb_w = (const float*)d_in[1];
  p.emb_b = (const float*)d_in[2];
  p.pos_emb = (const float*)d_in[3];
  p.cls_emb = (const float*)d_in[4];
  p.ipw = (const float*)d_in[5];
  p.ipb = (const float*)d_in[6];
  p.aow = (const float*)d_in[7];
  p.aob = (const float*)d_in[8];
  p.fw1 = (const float*)d_in[9];
  p.fb1 = (const float*)d_in[10];
  p.fw2 = (const float*)d_in[11];
  p.fb2 = (const float*)d_in[12];
  p.ln1g = (const float*)d_in[13];
  p.ln1b = (const float*)d_in[14];
  p.ln2g = (const float*)d_in[15];
  p.ln2b = (const float*)d_in[16];
  p.out_w = (const float*)d_in[17];
  p.out_b = (const float*)d_in[18];
  p.ws = (float*)d_ws;
  float* out = (float*)d_out;
  float* logits = p.ws + 1184256;

  void* kargs[] = {(void*)&p};
  hipError_t err =
      hipLaunchCooperativeKernel(mega, dim3(GRID_), dim3(NT_), kargs, 0,
                                 stream);
  if (err != hipSuccess) {
    (void)hipGetLastError();  // clear sticky error; use non-coop fallback
    phase_wrap<<<dim3(GRID_), dim3(NT_), 0, stream>>>(p, 0, 0);
    for (int l = 0; l < 4; ++l)
      for (int ph = 1; ph <= 9; ++ph)
        phase_wrap<<<dim3(GRID_), dim3(NT_), 0, stream>>>(p, ph, l);
    phase_wrap<<<dim3(GRID_), dim3(NT_), 0, stream>>>(p, 10, 0);
    phase_wrap<<<dim3(GRID_), dim3(NT_), 0, stream>>>(p, 11, 0);
  }
  sinkhorn_kernel<<<dim3(1), dim3(1024), 0, stream>>>(logits, out);
}

// Round 10
// 2492.462 us; speedup vs baseline: 1.0054x; 1.0054x over previous
//
#include <hip/hip_runtime.h>
#include <hip/hip_cooperative_groups.h>
#include <math.h>

namespace cg = cooperative_groups;

#define S_ 257
#define D_ 512
#define MB_ 5    // ceil(257/64)
#define GRID_ 256
#define NT_ 512  // 8 waves/block = 2 waves/SIMD at 1 block/CU

struct MegaP {
  const float* in_x;
  const float* emb_w;
  const float* emb_b;
  const float* pos_emb;
  const float* cls_emb;
  const float* ipw;
  const float* ipb;
  const float* aow;
  const float* aob;
  const float* fw1;
  const float* fb1;
  const float* fw2;
  const float* fb2;
  const float* ln1g;
  const float* ln1b;
  const float* ln2g;
  const float* ln2b;
  const float* out_w;
  const float* out_b;
  float* ws;
};

using Tile = float[2][32][68];

// ---- embed row job (uniform barrier structure incl. row 0) -----------------
__device__ __forceinline__ void embed_job(int row, bool active, int tid,
                                          const MegaP& p, float* sbuf) {
  float* src = p.ws;
  if (active && row > 0 && tid < 64) sbuf[tid] = p.in_x[(row - 1) * 64 + tid];
  __syncthreads();
  if (active) {
    for (int j = tid; j < D_; j += 256) {
      float v;
      if (row == 0) {
        v = p.cls_emb[j] + p.pos_emb[j];
      } else {
        float acc = p.emb_b[j];
#pragma unroll 8
        for (int k = 0; k < 64; ++k) acc += sbuf[k] * p.emb_w[k * D_ + j];
        v = acc + p.pos_emb[row * D_ + j];
      }
      src[row * D_ + j] = v;
    }
  }
  __syncthreads();
}

// ---- proven 64x64 dbuf split-K GEMM, per 256-thread sub-block --------------
template <bool TRANSB>
__device__ __forceinline__ void gemm_job(int job, bool active, int tid,
                                         const float* __restrict__ A,
                                         const float* __restrict__ B,
                                         float* __restrict__ out, int M, int N,
                                         int K, int kslice, int nb, int MNtot,
                                         Tile& As, Tile& Bs) {
  const int by = job % MB_;
  const int t2 = job / MB_;
  const int bx = t2 % nb;
  const int bz = t2 / nb;
  const int m0 = by * 64, n0 = bx * 64, kbeg = bz * kslice;

  const int sm = tid & 63;
  const int sk = (tid >> 6) * 8;
  const int bk = tid >> 3;
  const int bn = (tid & 7) * 8;

  float4 ra0, ra1, rb0, rb1;
  const float4 z4 = make_float4(0.f, 0.f, 0.f, 0.f);

  auto loadT = [&](int k0) {
    const int gm = m0 + sm;
    if (gm < M) {
      const float* ptr = &A[(size_t)gm * K + k0 + sk];
      ra0 = *reinterpret_cast<const float4*>(ptr);
      ra1 = *reinterpret_cast<const float4*>(ptr + 4);
    } else {
      ra0 = z4;
      ra1 = z4;
    }
    if (TRANSB) {
      const float* ptr = &B[(size_t)(n0 + sm) * K + k0 + sk];
      rb0 = *reinterpret_cast<const float4*>(ptr);
      rb1 = *reinterpret_cast<const float4*>(ptr + 4);
    } else {
      const float* ptr = &B[(size_t)(k0 + bk) * N + n0 + bn];
      rb0 = *reinterpret_cast<const float4*>(ptr);
      rb1 = *reinterpret_cast<const float4*>(ptr + 4);
    }
  };
  auto storeT = [&](int b) {
    As[b][sk + 0][sm] = ra0.x;
    As[b][sk + 1][sm] = ra0.y;
    As[b][sk + 2][sm] = ra0.z;
    As[b][sk + 3][sm] = ra0.w;
    As[b][sk + 4][sm] = ra1.x;
    As[b][sk + 5][sm] = ra1.y;
    As[b][sk + 6][sm] = ra1.z;
    As[b][sk + 7][sm] = ra1.w;
    if (TRANSB) {
      Bs[b][sk + 0][sm] = rb0.x;
      Bs[b][sk + 1][sm] = rb0.y;
      Bs[b][sk + 2][sm] = rb0.z;
      Bs[b][sk + 3][sm] = rb0.w;
      Bs[b][sk + 4][sm] = rb1.x;
      Bs[b][sk + 5][sm] = rb1.y;
      Bs[b][sk + 6][sm] = rb1.z;
      Bs[b][sk + 7][sm] = rb1.w;
    } else {
      *reinterpret_cast<float4*>(&Bs[b][bk][bn]) = rb0;
      *reinterpret_cast<float4*>(&Bs[b][bk][bn + 4]) = rb1;
    }
  };

  float acc[4][4] = {};
  const int tx4 = (tid & 15) * 4;
  const int ty4 = (tid >> 4) * 4;

  const int nt = kslice >> 5;
  loadT(kbeg);
  storeT(0);
  __syncthreads();
  int buf = 0;
  for (int t = 0; t < nt; ++t) {
    const bool more = (t + 1 < nt);
    if (more) loadT(kbeg + (t + 1) * 32);
#pragma unroll
    for (int k = 0; k < 32; ++k) {
      const float4 av = *reinterpret_cast<const float4*>(&As[buf][k][ty4]);
      const float4 bv = *reinterpret_cast<const float4*>(&Bs[buf][k][tx4]);
      acc[0][0] += av.x * bv.x;
      acc[0][1] += av.x * bv.y;
      acc[0][2] += av.x * bv.z;
      acc[0][3] += av.x * bv.w;
      acc[1][0] += av.y * bv.x;
      acc[1][1] += av.y * bv.y;
      acc[1][2] += av.y * bv.z;
      acc[1][3] += av.y * bv.w;
      acc[2][0] += av.z * bv.x;
      acc[2][1] += av.z * bv.y;
      acc[2][2] += av.z * bv.z;
      acc[2][3] += av.z * bv.w;
      acc[3][0] += av.w * bv.x;
      acc[3][1] += av.w * bv.y;
      acc[3][2] += av.w * bv.z;
      acc[3][3] += av.w * bv.w;
    }
    if (more) storeT(buf ^ 1);
    __syncthreads();
    buf ^= 1;
  }

  if (active) {
    float* pb = out + (size_t)bz * MNtot;
#pragma unroll
    for (int i = 0; i < 4; ++i) {
      const int m = m0 + ty4 + i;
      if (m >= M) break;
      *reinterpret_cast<float4*>(&pb[(size_t)m * N + n0 + tx4]) =
          make_float4(acc[i][0], acc[i][1], acc[i][2], acc[i][3]);
    }
  }
  __syncthreads();
}

// ---- attention job (one query row per 256-thread sub-block) ----------------
__device__ __forceinline__ void attn_job(int q, bool active, int tid,
                                         const float* __restrict__ qkv,
                                         float* __restrict__ attnO,
                                         float (*sc)[260], float (*qsh)[64]) {
  const int lane = tid & 31;
  const int hg = tid >> 5;
  {
    const int e = tid * 2;
    const float2 v =
        *reinterpret_cast<const float2*>(&qkv[(size_t)q * 1536 + e]);
    qsh[e >> 6][e & 63] = v.x;
    qsh[e >> 6][(e & 63) + 1] = v.y;
  }
  __syncthreads();
  float lm = -1e30f;
  for (int j = lane; j < S_; j += 32) {
    const float4* kr =
        reinterpret_cast<const float4*>(&qkv[(size_t)j * 1536 + 512 + hg * 64]);
    const float4* qr = reinterpret_cast<const float4*>(&qsh[hg][0]);
    float acc = 0.f;
#pragma unroll
    for (int d = 0; d < 16; ++d) {
      const float4 kk = kr[d], qq = qr[d];
      acc += kk.x * qq.x + kk.y * qq.y + kk.z * qq.z + kk.w * qq.w;
    }
    const float s = acc * 0.125f;
    sc[hg][j] = s;
    lm = fmaxf(lm, s);
  }
#pragma unroll
  for (int off = 16; off > 0; off >>= 1)
    lm = fmaxf(lm, __shfl_xor(lm, off, 32));
  float ls = 0.f;
  for (int j = lane; j < S_; j += 32) {
    const float pw = __expf(sc[hg][j] - lm);
    sc[hg][j] = pw;
    ls += pw;
  }
#pragma unroll
  for (int off = 16; off > 0; off >>= 1) ls += __shfl_xor(ls, off, 32);
  const float inv = 1.f / ls;
  __syncthreads();
  float a0 = 0.f, a1 = 0.f;
#pragma unroll 4
  for (int j = 0; j < S_; ++j) {
    const float pw = sc[hg][j];
    const float2 vv = *reinterpret_cast<const float2*>(
        &qkv[(size_t)j * 1536 + 1024 + hg * 64 + lane * 2]);
    a0 += pw * vv.x;
    a1 += pw * vv.y;
  }
  if (active)
    *reinterpret_cast<float2*>(&attnO[(size_t)q * D_ + hg * 64 + lane * 2]) =
        make_float2(a0 * inv, a1 * inv);
  __syncthreads();
}

// ---- split-K reduce + bias + residual + LayerNorm row job ------------------
__device__ __forceinline__ void ln_job(int row, bool active, int tid,
                                       const float* __restrict__ part, int S,
                                       const float* __restrict__ bias,
                                       float* __restrict__ io,
                                       const float* __restrict__ gg,
                                       const float* __restrict__ bb,
                                       float* redA, float* redB) {
  const size_t base = (size_t)row * D_;
  float x0 = io[base + tid] + bias[tid];
  float x1 = io[base + 256 + tid] + bias[256 + tid];
  for (int s = 0; s < S; ++s) {
    x0 += part[(size_t)s * (size_t)(S_ * D_) + base + tid];
    x1 += part[(size_t)s * (size_t)(S_ * D_) + base + 256 + tid];
  }
  float sm = x0 + x1;
#pragma unroll
  for (int off = 32; off > 0; off >>= 1) sm += __shfl_down(sm, off);
  if ((tid & 63) == 0) redA[tid >> 6] = sm;
  __syncthreads();
  const float mu = (redA[0] + redA[1] + redA[2] + redA[3]) * (1.f / 512.f);
  const float d0 = x0 - mu, d1 = x1 - mu;
  float qv = d0 * d0 + d1 * d1;
#pragma unroll
  for (int off = 32; off > 0; off >>= 1) qv += __shfl_down(qv, off);
  if ((tid & 63) == 0) redB[tid >> 6] = qv;
  __syncthreads();
  const float var = (redB[0] + redB[1] + redB[2] + redB[3]) * (1.f / 512.f);
  const float inv = rsqrtf(var + 1e-5f);
  if (active) {
    io[base + tid] = d0 * inv * gg[tid] + bb[tid];
    io[base + 256 + tid] = d1 * inv * gg[256 + tid] + bb[256 + tid];
  }
  __syncthreads();
}

// ---- head gemv job ---------------------------------------------------------
__device__ __forceinline__ void gemv_job(int job, int tid,
                                         const float* __restrict__ src,
                                         const float* __restrict__ out_w,
                                         float* __restrict__ part,
                                         float* __restrict__ sbuf) {
  const int jc = job & 63;
  const int dc = job >> 6;
  if (tid < 64) sbuf[tid] = src[dc * 64 + tid];
  __syncthreads();
  const int j0 = jc * 1024 + tid * 4;
  float4 acc = make_float4(0.f, 0.f, 0.f, 0.f);
  for (int d = 0; d < 64; ++d) {
    const float sv = sbuf[d];
    const float4 w = *reinterpret_cast<const float4*>(
        &out_w[(size_t)(dc * 64 + d) * 65536 + j0]);
    acc.x += sv * w.x;
    acc.y += sv * w.y;
    acc.z += sv * w.z;
    acc.w += sv * w.w;
  }
  *reinterpret_cast<float4*>(&part[(size_t)dc * 65536 + j0]) = acc;
  __syncthreads();
}

// ---- barrier-free grid-stride reduce (+bias, opt relu) ---------------------
__device__ __forceinline__ void reduce_phase(int bid, int tid512,
                                             const float* __restrict__ part,
                                             const float* __restrict__ bias,
                                             float* __restrict__ out, int MN4,
                                             int N4, int S, int relu) {
  for (int i = bid * NT_ + tid512; i < MN4; i += GRID_ * NT_) {
    float4 acc = reinterpret_cast<const float4*>(bias)[i % N4];
    for (int s = 0; s < S; ++s) {
      const float4 v =
          reinterpret_cast<const float4*>(part)[(size_t)s * MN4 + i];
      acc.x += v.x;
      acc.y += v.y;
      acc.z += v.z;
      acc.w += v.w;
    }
    if (relu) {
      acc.x = fmaxf(acc.x, 0.f);
      acc.y = fmaxf(acc.y, 0.f);
      acc.z = fmaxf(acc.z, 0.f);
      acc.w = fmaxf(acc.w, 0.f);
    }
    reinterpret_cast<float4*>(out)[i] = acc;
  }
}

// ---- one phase of the pipeline (shared by mega and fallback wrapper) -------
__device__ void run_phase(int phase, int l, const MegaP& p, int bid, int g,
                          int tid, int tid512, Tile& As, Tile& Bs,
                          float (*sc)[260], float (*qsh)[64], float* redA,
                          float* redB, float* sbuf) {
  float* ws = p.ws;
  float* src = ws;               // 257*512
  float* qkv = ws + 131584;      // 257*1536
  float* attnO = ws + 526336;    // 257*512
  float* ffh = ws + 657920;      // 257*2048
  float* logits = ws + 1184256;  // 65536
  float* part = ws + 1249792;    // up to 4*394752
  const int jr = bid * 2 + g;    // sub-block job slot (uniform per sub-block)
  switch (phase) {
    case 0: {
      const bool a = jr < S_;
      embed_job(a ? jr : S_ - 1, a, tid, p, sbuf);
    } break;
    case 1: {  // qkv partials: splitK4, 480 jobs, nt=4
      const bool a = jr < 480;
      gemm_job<true>(a ? jr : 479, a, tid, src,
                     p.ipw + (size_t)l * 1536 * 512, part, S_, 1536, 512, 128,
                     24, S_ * 1536, As, Bs);
    } break;
    case 2:  // qkv reduce + bias
      reduce_phase(bid, tid512, part, p.ipb + l * 1536, qkv, (S_ * 1536) / 4,
                   384, 4, 0);
      break;
    case 3: {
      const bool a = jr < S_;
      attn_job(a ? jr : S_ - 1, a, tid, qkv, attnO, sc, qsh);
    } break;
    case 4: {  // proj partials: splitK8, 320 jobs, nt=2
      const bool a = jr < 320;
      gemm_job<true>(a ? jr : 319, a, tid, attnO,
                     p.aow + (size_t)l * 512 * 512, part, S_, 512, 512, 64, 8,
                     S_ * D_, As, Bs);
    } break;
    case 5: {
      const bool a = jr < S_;
      ln_job(a ? jr : S_ - 1, a, tid, part, 8, p.aob + l * 512, src,
             p.ln1g + l * 512, p.ln1b + l * 512, redA, redB);
    } break;
    case 6: {  // ff1 partials: splitK2, 320 jobs, nt=8
      const bool a = jr < 320;
      gemm_job<false>(a ? jr : 319, a, tid, src,
                      p.fw1 + (size_t)l * 512 * 2048, part, S_, 2048, 512, 256,
                      32, S_ * 2048, As, Bs);
    } break;
    case 7:  // ff1 reduce + bias + relu
      reduce_phase(bid, tid512, part, p.fb1 + l * 2048, ffh, (S_ * 2048) / 4,
                   512, 2, 1);
      break;
    case 8: {  // ff2 partials: splitK8, 320 jobs, nt=8
      const bool a = jr < 320;
      gemm_job<false>(a ? jr : 319, a, tid, ffh,
                      p.fw2 + (size_t)l * 2048 * 512, part, S_, 512, 2048, 256,
                      8, S_ * D_, As, Bs);
    } break;
    case 9: {
      const bool a = jr < S_;
      ln_job(a ? jr : S_ - 1, a, tid, part, 8, p.fb2 + l * 512, src,
             p.ln2g + l * 512, p.ln2b + l * 512, redA, redB);
    } break;
    case 10:  // head gemv: 512 jobs
      gemv_job(jr, tid, src, p.out_w, part, sbuf);
      break;
    case 11:  // logits = sum(8 parts) + out_b
      reduce_phase(bid, tid512, part, p.out_b, logits, 16384, 16384, 8, 0);
      break;
  }
}

// ---- the megakernel: 512 threads = two 256-thread sub-blocks ---------------
// (NT_,1): VGPR cap 256 (datapath needs ~190). (NT_,2) capped at 128 and
// spilled 2.9 GB of scratch traffic (rounds 3/7/9 all hit this same cliff).
__global__ __launch_bounds__(NT_, 1) void mega(MegaP p) {
  cg::grid_group grid = cg::this_grid();
  const int bid = blockIdx.x;
  const int tid512 = threadIdx.x;
  const int g = tid512 >> 8;
  const int tid = tid512 & 255;

  __shared__ __align__(16) float As[2][2][32][68];
  __shared__ __align__(16) float Bs[2][2][32][68];
  __shared__ __align__(16) float sc[2][8][260];
  __shared__ __align__(16) float qsh[2][8][64];
  __shared__ float redA[2][4], redB[2][4];
  __shared__ __align__(16) float sbuf[2][64];

  run_phase(0, 0, p, bid, g, tid, tid512, As[g], Bs[g], sc[g], qsh[g], redA[g],
            redB[g], sbuf[g]);
  grid.sync();
  for (int l = 0; l < 4; ++l) {
    for (int ph = 1; ph <= 9; ++ph) {
      run_phase(ph, l, p, bid, g, tid, tid512, As[g], Bs[g], sc[g], qsh[g],
                redA[g], redB[g], sbuf[g]);
      grid.sync();
    }
  }
  run_phase(10, 0, p, bid, g, tid, tid512, As[g], Bs[g], sc[g], qsh[g],
            redA[g], redB[g], sbuf[g]);
  grid.sync();
  run_phase(11, 0, p, bid, g, tid, tid512, As[g], Bs[g], sc[g], qsh[g],
            redA[g], redB[g], sbuf[g]);
}

// ---- fallback: one phase per launch, same code path ------------------------
__global__ __launch_bounds__(NT_, 1) void phase_wrap(MegaP p, int phase,
                                                     int l) {
  const int bid = blockIdx.x;
  const int tid512 = threadIdx.x;
  const int g = tid512 >> 8;
  const int tid = tid512 & 255;
  __shared__ __align__(16) float As[2][2][32][68];
  __shared__ __align__(16) float Bs[2][2][32][68];
  __shared__ __align__(16) float sc[2][8][260];
  __shared__ __align__(16) float qsh[2][8][64];
  __shared__ float redA[2][4], redB[2][4];
  __shared__ __align__(16) float sbuf[2][64];
  run_phase(phase, l, p, bid, g, tid, tid512, As[g], Bs[g], sc[g], qsh[g],
            redA[g], redB[g], sbuf[g]);
}

// ---------------- sinkhorn (rank-1 reformulation, unchanged) ----------------
__global__ __launch_bounds__(1024) void sinkhorn_kernel(
    const float* __restrict__ logits, float* __restrict__ out) {
  const int tid = threadIdx.x;
  const int tx = tid & 31;
  const int ty = tid >> 5;
  const int i0 = ty * 8, j0 = tx * 8;
  float E[8][8];
#pragma unroll
  for (int ii = 0; ii < 8; ++ii) {
    const float4 a =
        *reinterpret_cast<const float4*>(&logits[(i0 + ii) * 256 + j0]);
    const float4 b =
        *reinterpret_cast<const float4*>(&logits[(i0 + ii) * 256 + j0 + 4]);
    E[ii][0] = __expf(a.x);
    E[ii][1] = __expf(a.y);
    E[ii][2] = __expf(a.z);
    E[ii][3] = __expf(a.w);
    E[ii][4] = __expf(b.x);
    E[ii][5] = __expf(b.y);
    E[ii][6] = __expf(b.z);
    E[ii][7] = __expf(b.w);
  }
  __shared__ float part[32][8][32];
  __shared__ int partI[32][8][32];
  __shared__ float uu[256];
  __shared__ float vv[256];
  __shared__ int amax[256];
  if (tid < 256) uu[tid] = 1.f;
  __syncthreads();
  for (int it = 0; it < 20; ++it) {
    float ul[8];
#pragma unroll
    for (int ii = 0; ii < 8; ++ii) ul[ii] = uu[i0 + ii];
#pragma unroll
    for (int jj = 0; jj < 8; ++jj) {
      float s = 0.f;
#pragma unroll
      for (int ii = 0; ii < 8; ++ii) s += E[ii][jj] * ul[ii];
      part[ty][jj][tx] = s;
    }
    __syncthreads();
    if (tid < 256) {
      const int jj = tid >> 5, txr = tid & 31;
      float s = 0.f;
#pragma unroll
      for (int pp = 0; pp < 32; ++pp) s += part[pp][jj][txr];
      vv[txr * 8 + jj] = 1.f / s;
    }
    __syncthreads();
    float vl[8];
#pragma unroll
    for (int jj = 0; jj < 8; ++jj) vl[jj] = vv[j0 + jj];
#pragma unroll
    for (int ii = 0; ii < 8; ++ii) {
      float s = 0.f;
#pragma unroll
      for (int jj = 0; jj < 8; ++jj) s += E[ii][jj] * vl[jj];
      part[ty][ii][tx] = s;
    }
    __syncthreads();
    if (tid < 256) {
      const int i = tid;
      float s = 0.f;
#pragma unroll
      for (int pp = 0; pp < 32; ++pp) {
        const int pr = (pp + i) & 31;
        s += part[i >> 3][i & 7][pr];
      }
      uu[i] = 1.f / s;
    }
    __syncthreads();
  }
  float ul[8], vl[8];
#pragma unroll
  for (int ii = 0; ii < 8; ++ii) ul[ii] = uu[i0 + ii];
#pragma unroll
  for (int jj = 0; jj < 8; ++jj) vl[jj] = vv[j0 + jj];
#pragma unroll
  for (int ii = 0; ii < 8; ++ii) {
    float vals[8];
    float best = -1.f;
    int bidx = 0;
#pragma unroll
    for (int jj = 0; jj < 8; ++jj) {
      const float pv = E[ii][jj] * ul[ii] * vl[jj];
      vals[jj] = pv;
      if (pv > best) {
        best = pv;
        bidx = j0 + jj;
      }
    }
    *reinterpret_cast<float4*>(&out[(i0 + ii) * 256 + j0]) =
        make_float4(vals[0], vals[1], vals[2], vals[3]);
    *reinterpret_cast<float4*>(&out[(i0 + ii) * 256 + j0 + 4]) =
        make_float4(vals[4], vals[5], vals[6], vals[7]);
    part[ty][ii][tx] = best;
    partI[ty][ii][tx] = bidx;
  }
  __syncthreads();
  if (tid < 256) {
    const int i = tid;
    float best = -1.f;
    int bidx = 1 << 30;
#pragma unroll
    for (int pp = 0; pp < 32; ++pp) {
      const int pr = (pp + i) & 31;
      const float v = part[i >> 3][i & 7][pr];
      const int ix = partI[i >> 3][i & 7][pr];
      if (v > best || (v == best && ix < bidx)) {
        best = v;
        bidx = ix;
      }
    }
    amax[i] = bidx;
  }
  __syncthreads();
#pragma unroll
  for (int ii = 0; ii < 8; ++ii) {
    const int am = amax[i0 + ii];
    float4 h0, h1;
    h0.x = (j0 + 0 == am) ? 1.f : 0.f;
    h0.y = (j0 + 1 == am) ? 1.f : 0.f;
    h0.z = (j0 + 2 == am) ? 1.f : 0.f;
    h0.w = (j0 + 3 == am) ? 1.f : 0.f;
    h1.x = (j0 + 4 == am) ? 1.f : 0.f;
    h1.y = (j0 + 5 == am) ? 1.f : 0.f;
    h1.z = (j0 + 6 == am) ? 1.f : 0.f;
    h1.w = (j0 + 7 == am) ? 1.f : 0.f;
    *reinterpret_cast<float4*>(&out[65536 + (i0 + ii) * 256 + j0]) = h0;
    *reinterpret_cast<float4*>(&out[65536 + (i0 + ii) * 256 + j0 + 4]) = h1;
  }
}

// ---------------- host-side launch ------------------------------------------
extern "C" void kernel_launch(void* const* d_in, const int* in_sizes, int n_in,
                              void* d_out, int out_size, void* d_ws,
                              size_t ws_size, hipStream_t stream) {
  (void)in_sizes;
  (void)n_in;
  (void)out_size;
  (void)ws_size;
  MegaP p;
  p.in_x = (const float*)d_in[0];
  p.emb_w = (const float*)d_in[1];
  p.emb_b = (const float*)d_in[2];
  p.pos_emb = (const float*)d_in[3];
  p.cls_emb = (const float*)d_in[4];
  p.ipw = (const float*)d_in[5];
  p.ipb = (const float*)d_in[6];
  p.aow = (const float*)d_in[7];
  p.aob = (const float*)d_in[8];
  p.fw1 = (const float*)d_in[9];
  p.fb1 = (const float*)d_in[10];
  p.fw2 = (const float*)d_in[11];
  p.fb2 = (const float*)d_in[12];
  p.ln1g = (const float*)d_in[13];
  p.ln1b = (const float*)d_in[14];
  p.ln2g = (const float*)d_in[15];
  p.ln2b = (const float*)d_in[16];
  p.out_w = (const float*)d_in[17];
  p.out_b = (const float*)d_in[18];
  p.ws = (float*)d_ws;
  float* out = (float*)d_out;
  float* logits = p.ws + 1184256;

  void* kargs[] = {(void*)&p};
  hipError_t err =
      hipLaunchCooperativeKernel(mega, dim3(GRID_), dim3(NT_), kargs, 0,
                                 stream);
  if (err != hipSuccess) {
    (void)hipGetLastError();  // clear sticky error; use non-coop fallback
    phase_wrap<<<dim3(GRID_), dim3(NT_), 0, stream>>>(p, 0, 0);
    for (int l = 0; l < 4; ++l)
      for (int ph = 1; ph <= 9; ++ph)
        phase_wrap<<<dim3(GRID_), dim3(NT_), 0, stream>>>(p, ph, l);
    phase_wrap<<<dim3(GRID_), dim3(NT_), 0, stream>>>(p, 10, 0);
    phase_wrap<<<dim3(GRID_), dim3(NT_), 0, stream>>>(p, 11, 0);
  }
  sinkhorn_kernel<<<dim3(1), dim3(1024), 0, stream>>>(logits, out);
}

// Round 11
// 2446.286 us; speedup vs baseline: 1.0244x; 1.0189x over previous
//
#include <hip/hip_runtime.h>
#include <hip/hip_cooperative_groups.h>
#include <math.h>

namespace cg = cooperative_groups;

#define S_ 257
#define D_ 512
#define MB_ 5    // ceil(257/64)
#define GRID_ 256
#define NT_ 512  // 8 waves/block = 2 waves/SIMD at 1 block/CU

struct MegaP {
  const float* in_x;
  const float* emb_w;
  const float* emb_b;
  const float* pos_emb;
  const float* cls_emb;
  const float* ipw;
  const float* ipb;
  const float* aow;
  const float* aob;
  const float* fw1;
  const float* fb1;
  const float* fw2;
  const float* fb2;
  const float* ln1g;
  const float* ln1b;
  const float* ln2g;
  const float* ln2b;
  const float* out_w;
  const float* out_b;
  float* ws;
};

using Tile = float[2][32][68];

// ---- embed row job (uniform barrier structure incl. row 0) -----------------
__device__ __forceinline__ void embed_job(int row, bool active, int tid,
                                          const MegaP& p, float* sbuf) {
  float* src = p.ws;
  if (active && row > 0 && tid < 64) sbuf[tid] = p.in_x[(row - 1) * 64 + tid];
  __syncthreads();
  if (active) {
    for (int j = tid; j < D_; j += 256) {
      float v;
      if (row == 0) {
        v = p.cls_emb[j] + p.pos_emb[j];
      } else {
        float acc = p.emb_b[j];
#pragma unroll 8
        for (int k = 0; k < 64; ++k) acc += sbuf[k] * p.emb_w[k * D_ + j];
        v = acc + p.pos_emb[row * D_ + j];
      }
      src[row * D_ + j] = v;
    }
  }
  __syncthreads();
}

// ---- proven 64x64 dbuf split-K GEMM, per 256-thread sub-block --------------
template <bool TRANSB>
__device__ __forceinline__ void gemm_job(int job, bool active, int tid,
                                         const float* __restrict__ A,
                                         const float* __restrict__ B,
                                         float* __restrict__ out, int M, int N,
                                         int K, int kslice, int nb, int MNtot,
                                         Tile& As, Tile& Bs) {
  const int by = job % MB_;
  const int t2 = job / MB_;
  const int bx = t2 % nb;
  const int bz = t2 / nb;
  const int m0 = by * 64, n0 = bx * 64, kbeg = bz * kslice;

  const int sm = tid & 63;
  const int sk = (tid >> 6) * 8;
  const int bk = tid >> 3;
  const int bn = (tid & 7) * 8;

  float4 ra0, ra1, rb0, rb1;
  const float4 z4 = make_float4(0.f, 0.f, 0.f, 0.f);

  auto loadT = [&](int k0) {
    const int gm = m0 + sm;
    if (gm < M) {
      const float* ptr = &A[(size_t)gm * K + k0 + sk];
      ra0 = *reinterpret_cast<const float4*>(ptr);
      ra1 = *reinterpret_cast<const float4*>(ptr + 4);
    } else {
      ra0 = z4;
      ra1 = z4;
    }
    if (TRANSB) {
      const float* ptr = &B[(size_t)(n0 + sm) * K + k0 + sk];
      rb0 = *reinterpret_cast<const float4*>(ptr);
      rb1 = *reinterpret_cast<const float4*>(ptr + 4);
    } else {
      const float* ptr = &B[(size_t)(k0 + bk) * N + n0 + bn];
      rb0 = *reinterpret_cast<const float4*>(ptr);
      rb1 = *reinterpret_cast<const float4*>(ptr + 4);
    }
  };
  auto storeT = [&](int b) {
    As[b][sk + 0][sm] = ra0.x;
    As[b][sk + 1][sm] = ra0.y;
    As[b][sk + 2][sm] = ra0.z;
    As[b][sk + 3][sm] = ra0.w;
    As[b][sk + 4][sm] = ra1.x;
    As[b][sk + 5][sm] = ra1.y;
    As[b][sk + 6][sm] = ra1.z;
    As[b][sk + 7][sm] = ra1.w;
    if (TRANSB) {
      Bs[b][sk + 0][sm] = rb0.x;
      Bs[b][sk + 1][sm] = rb0.y;
      Bs[b][sk + 2][sm] = rb0.z;
      Bs[b][sk + 3][sm] = rb0.w;
      Bs[b][sk + 4][sm] = rb1.x;
      Bs[b][sk + 5][sm] = rb1.y;
      Bs[b][sk + 6][sm] = rb1.z;
      Bs[b][sk + 7][sm] = rb1.w;
    } else {
      *reinterpret_cast<float4*>(&Bs[b][bk][bn]) = rb0;
      *reinterpret_cast<float4*>(&Bs[b][bk][bn + 4]) = rb1;
    }
  };

  float acc[4][4] = {};
  const int tx4 = (tid & 15) * 4;
  const int ty4 = (tid >> 4) * 4;

  const int nt = kslice >> 5;
  loadT(kbeg);
  storeT(0);
  __syncthreads();
  int buf = 0;
  for (int t = 0; t < nt; ++t) {
    const bool more = (t + 1 < nt);
    if (more) loadT(kbeg + (t + 1) * 32);
#pragma unroll
    for (int k = 0; k < 32; ++k) {
      const float4 av = *reinterpret_cast<const float4*>(&As[buf][k][ty4]);
      const float4 bv = *reinterpret_cast<const float4*>(&Bs[buf][k][tx4]);
      acc[0][0] += av.x * bv.x;
      acc[0][1] += av.x * bv.y;
      acc[0][2] += av.x * bv.z;
      acc[0][3] += av.x * bv.w;
      acc[1][0] += av.y * bv.x;
      acc[1][1] += av.y * bv.y;
      acc[1][2] += av.y * bv.z;
      acc[1][3] += av.y * bv.w;
      acc[2][0] += av.z * bv.x;
      acc[2][1] += av.z * bv.y;
      acc[2][2] += av.z * bv.z;
      acc[2][3] += av.z * bv.w;
      acc[3][0] += av.w * bv.x;
      acc[3][1] += av.w * bv.y;
      acc[3][2] += av.w * bv.z;
      acc[3][3] += av.w * bv.w;
    }
    if (more) storeT(buf ^ 1);
    __syncthreads();
    buf ^= 1;
  }

  if (active) {
    float* pb = out + (size_t)bz * MNtot;
#pragma unroll
    for (int i = 0; i < 4; ++i) {
      const int m = m0 + ty4 + i;
      if (m >= M) break;
      *reinterpret_cast<float4*>(&pb[(size_t)m * N + n0 + tx4]) =
          make_float4(acc[i][0], acc[i][1], acc[i][2], acc[i][3]);
    }
  }
  __syncthreads();
}

// ---- attention job (one query row per 256-thread sub-block) ----------------
__device__ __forceinline__ void attn_job(int q, bool active, int tid,
                                         const float* __restrict__ qkv,
                                         float* __restrict__ attnO,
                                         float (*sc)[260], float (*qsh)[64]) {
  const int lane = tid & 31;
  const int hg = tid >> 5;
  {
    const int e = tid * 2;
    const float2 v =
        *reinterpret_cast<const float2*>(&qkv[(size_t)q * 1536 + e]);
    qsh[e >> 6][e & 63] = v.x;
    qsh[e >> 6][(e & 63) + 1] = v.y;
  }
  __syncthreads();
  float lm = -1e30f;
  for (int j = lane; j < S_; j += 32) {
    const float4* kr =
        reinterpret_cast<const float4*>(&qkv[(size_t)j * 1536 + 512 + hg * 64]);
    const float4* qr = reinterpret_cast<const float4*>(&qsh[hg][0]);
    float acc = 0.f;
#pragma unroll
    for (int d = 0; d < 16; ++d) {
      const float4 kk = kr[d], qq = qr[d];
      acc += kk.x * qq.x + kk.y * qq.y + kk.z * qq.z + kk.w * qq.w;
    }
    const float s = acc * 0.125f;
    sc[hg][j] = s;
    lm = fmaxf(lm, s);
  }
#pragma unroll
  for (int off = 16; off > 0; off >>= 1)
    lm = fmaxf(lm, __shfl_xor(lm, off, 32));
  float ls = 0.f;
  for (int j = lane; j < S_; j += 32) {
    const float pw = __expf(sc[hg][j] - lm);
    sc[hg][j] = pw;
    ls += pw;
  }
#pragma unroll
  for (int off = 16; off > 0; off >>= 1) ls += __shfl_xor(ls, off, 32);
  const float inv = 1.f / ls;
  __syncthreads();
  float a0 = 0.f, a1 = 0.f;
#pragma unroll 4
  for (int j = 0; j < S_; ++j) {
    const float pw = sc[hg][j];
    const float2 vv = *reinterpret_cast<const float2*>(
        &qkv[(size_t)j * 1536 + 1024 + hg * 64 + lane * 2]);
    a0 += pw * vv.x;
    a1 += pw * vv.y;
  }
  if (active)
    *reinterpret_cast<float2*>(&attnO[(size_t)q * D_ + hg * 64 + lane * 2]) =
        make_float2(a0 * inv, a1 * inv);
  __syncthreads();
}

// ---- split-K reduce + bias + residual + LayerNorm row job ------------------
__device__ __forceinline__ void ln_job(int row, bool active, int tid,
                                       const float* __restrict__ part, int S,
                                       const float* __restrict__ bias,
                                       float* __restrict__ io,
                                       const float* __restrict__ gg,
                                       const float* __restrict__ bb,
                                       float* redA, float* redB) {
  const size_t base = (size_t)row * D_;
  float x0 = io[base + tid] + bias[tid];
  float x1 = io[base + 256 + tid] + bias[256 + tid];
  for (int s = 0; s < S; ++s) {
    x0 += part[(size_t)s * (size_t)(S_ * D_) + base + tid];
    x1 += part[(size_t)s * (size_t)(S_ * D_) + base + 256 + tid];
  }
  float sm = x0 + x1;
#pragma unroll
  for (int off = 32; off > 0; off >>= 1) sm += __shfl_down(sm, off);
  if ((tid & 63) == 0) redA[tid >> 6] = sm;
  __syncthreads();
  const float mu = (redA[0] + redA[1] + redA[2] + redA[3]) * (1.f / 512.f);
  const float d0 = x0 - mu, d1 = x1 - mu;
  float qv = d0 * d0 + d1 * d1;
#pragma unroll
  for (int off = 32; off > 0; off >>= 1) qv += __shfl_down(qv, off);
  if ((tid & 63) == 0) redB[tid >> 6] = qv;
  __syncthreads();
  const float var = (redB[0] + redB[1] + redB[2] + redB[3]) * (1.f / 512.f);
  const float inv = rsqrtf(var + 1e-5f);
  if (active) {
    io[base + tid] = d0 * inv * gg[tid] + bb[tid];
    io[base + 256 + tid] = d1 * inv * gg[256 + tid] + bb[256 + tid];
  }
  __syncthreads();
}

// ---- head gemv job ---------------------------------------------------------
__device__ __forceinline__ void gemv_job(int job, int tid,
                                         const float* __restrict__ src,
                                         const float* __restrict__ out_w,
                                         float* __restrict__ part,
                                         float* __restrict__ sbuf) {
  const int jc = job & 63;
  const int dc = job >> 6;
  if (tid < 64) sbuf[tid] = src[dc * 64 + tid];
  __syncthreads();
  const int j0 = jc * 1024 + tid * 4;
  float4 acc = make_float4(0.f, 0.f, 0.f, 0.f);
  for (int d = 0; d < 64; ++d) {
    const float sv = sbuf[d];
    const float4 w = *reinterpret_cast<const float4*>(
        &out_w[(size_t)(dc * 64 + d) * 65536 + j0]);
    acc.x += sv * w.x;
    acc.y += sv * w.y;
    acc.z += sv * w.z;
    acc.w += sv * w.w;
  }
  *reinterpret_cast<float4*>(&part[(size_t)dc * 65536 + j0]) = acc;
  __syncthreads();
}

// ---- barrier-free grid-stride reduce (+bias, opt relu) ---------------------
__device__ __forceinline__ void reduce_phase(int bid, int tid512,
                                             const float* __restrict__ part,
                                             const float* __restrict__ bias,
                                             float* __restrict__ out, int MN4,
                                             int N4, int S, int relu) {
  for (int i = bid * NT_ + tid512; i < MN4; i += GRID_ * NT_) {
    float4 acc = reinterpret_cast<const float4*>(bias)[i % N4];
    for (int s = 0; s < S; ++s) {
      const float4 v =
          reinterpret_cast<const float4*>(part)[(size_t)s * MN4 + i];
      acc.x += v.x;
      acc.y += v.y;
      acc.z += v.z;
      acc.w += v.w;
    }
    if (relu) {
      acc.x = fmaxf(acc.x, 0.f);
      acc.y = fmaxf(acc.y, 0.f);
      acc.z = fmaxf(acc.z, 0.f);
      acc.w = fmaxf(acc.w, 0.f);
    }
    reinterpret_cast<float4*>(out)[i] = acc;
  }
}

// ---- one phase of the pipeline (FORCEINLINE: r9/r10's non-inlined version
// compiled as a real call with a 128-VGPR callee budget -> 2.9 GB spill) -----
__device__ __forceinline__ void run_phase(int phase, int l, const MegaP& p,
                                          int bid, int g, int tid, int tid512,
                                          Tile& As, Tile& Bs, float (*sc)[260],
                                          float (*qsh)[64], float* redA,
                                          float* redB, float* sbuf) {
  float* ws = p.ws;
  float* src = ws;               // 257*512
  float* qkv = ws + 131584;      // 257*1536
  float* attnO = ws + 526336;    // 257*512
  float* ffh = ws + 657920;      // 257*2048
  float* logits = ws + 1184256;  // 65536
  float* part = ws + 1249792;    // up to 4*394752
  const int jr = bid * 2 + g;    // sub-block job slot (uniform per sub-block)
  switch (phase) {
    case 0: {
      const bool a = jr < S_;
      embed_job(a ? jr : S_ - 1, a, tid, p, sbuf);
    } break;
    case 1: {  // qkv partials: splitK4, 480 jobs, nt=4
      const bool a = jr < 480;
      gemm_job<true>(a ? jr : 479, a, tid, src,
                     p.ipw + (size_t)l * 1536 * 512, part, S_, 1536, 512, 128,
                     24, S_ * 1536, As, Bs);
    } break;
    case 2:  // qkv reduce + bias
      reduce_phase(bid, tid512, part, p.ipb + l * 1536, qkv, (S_ * 1536) / 4,
                   384, 4, 0);
      break;
    case 3: {
      const bool a = jr < S_;
      attn_job(a ? jr : S_ - 1, a, tid, qkv, attnO, sc, qsh);
    } break;
    case 4: {  // proj partials: splitK8, 320 jobs, nt=2
      const bool a = jr < 320;
      gemm_job<true>(a ? jr : 319, a, tid, attnO,
                     p.aow + (size_t)l * 512 * 512, part, S_, 512, 512, 64, 8,
                     S_ * D_, As, Bs);
    } break;
    case 5: {
      const bool a = jr < S_;
      ln_job(a ? jr : S_ - 1, a, tid, part, 8, p.aob + l * 512, src,
             p.ln1g + l * 512, p.ln1b + l * 512, redA, redB);
    } break;
    case 6: {  // ff1 partials: splitK2, 320 jobs, nt=8
      const bool a = jr < 320;
      gemm_job<false>(a ? jr : 319, a, tid, src,
                      p.fw1 + (size_t)l * 512 * 2048, part, S_, 2048, 512, 256,
                      32, S_ * 2048, As, Bs);
    } break;
    case 7:  // ff1 reduce + bias + relu
      reduce_phase(bid, tid512, part, p.fb1 + l * 2048, ffh, (S_ * 2048) / 4,
                   512, 2, 1);
      break;
    case 8: {  // ff2 partials: splitK8, 320 jobs, nt=8
      const bool a = jr < 320;
      gemm_job<false>(a ? jr : 319, a, tid, ffh,
                      p.fw2 + (size_t)l * 2048 * 512, part, S_, 512, 2048, 256,
                      8, S_ * D_, As, Bs);
    } break;
    case 9: {
      const bool a = jr < S_;
      ln_job(a ? jr : S_ - 1, a, tid, part, 8, p.fb2 + l * 512, src,
             p.ln2g + l * 512, p.ln2b + l * 512, redA, redB);
    } break;
    case 10:  // head gemv: 512 jobs
      gemv_job(jr, tid, src, p.out_w, part, sbuf);
      break;
    case 11:  // logits = sum(8 parts) + out_b
      reduce_phase(bid, tid512, part, p.out_b, logits, 16384, 16384, 8, 0);
      break;
  }
}

// ---- the megakernel: 512 threads = two 256-thread sub-blocks ---------------
// (NT_,1): VGPR cap 256 (datapath needs ~190 per r8's measured 188).
__global__ __launch_bounds__(NT_, 1) void mega(MegaP p) {
  cg::grid_group grid = cg::this_grid();
  const int bid = blockIdx.x;
  const int tid512 = threadIdx.x;
  const int g = tid512 >> 8;
  const int tid = tid512 & 255;

  __shared__ __align__(16) float As[2][2][32][68];
  __shared__ __align__(16) float Bs[2][2][32][68];
  __shared__ __align__(16) float sc[2][8][260];
  __shared__ __align__(16) float qsh[2][8][64];
  __shared__ float redA[2][4], redB[2][4];
  __shared__ __align__(16) float sbuf[2][64];

  run_phase(0, 0, p, bid, g, tid, tid512, As[g], Bs[g], sc[g], qsh[g], redA[g],
            redB[g], sbuf[g]);
  grid.sync();
  for (int l = 0; l < 4; ++l) {
    for (int ph = 1; ph <= 9; ++ph) {
      run_phase(ph, l, p, bid, g, tid, tid512, As[g], Bs[g], sc[g], qsh[g],
                redA[g], redB[g], sbuf[g]);
      grid.sync();
    }
  }
  run_phase(10, 0, p, bid, g, tid, tid512, As[g], Bs[g], sc[g], qsh[g],
            redA[g], redB[g], sbuf[g]);
  grid.sync();
  run_phase(11, 0, p, bid, g, tid, tid512, As[g], Bs[g], sc[g], qsh[g],
            redA[g], redB[g], sbuf[g]);
}

// ---- fallback: one phase per launch, same code path ------------------------
__global__ __launch_bounds__(NT_, 1) void phase_wrap(MegaP p, int phase,
                                                     int l) {
  const int bid = blockIdx.x;
  const int tid512 = threadIdx.x;
  const int g = tid512 >> 8;
  const int tid = tid512 & 255;
  __shared__ __align__(16) float As[2][2][32][68];
  __shared__ __align__(16) float Bs[2][2][32][68];
  __shared__ __align__(16) float sc[2][8][260];
  __shared__ __align__(16) float qsh[2][8][64];
  __shared__ float redA[2][4], redB[2][4];
  __shared__ __align__(16) float sbuf[2][64];
  run_phase(phase, l, p, bid, g, tid, tid512, As[g], Bs[g], sc[g], qsh[g],
            redA[g], redB[g], sbuf[g]);
}

// ---------------- sinkhorn (rank-1 reformulation, unchanged) ----------------
__global__ __launch_bounds__(1024) void sinkhorn_kernel(
    const float* __restrict__ logits, float* __restrict__ out) {
  const int tid = threadIdx.x;
  const int tx = tid & 31;
  const int ty = tid >> 5;
  const int i0 = ty * 8, j0 = tx * 8;
  float E[8][8];
#pragma unroll
  for (int ii = 0; ii < 8; ++ii) {
    const float4 a =
        *reinterpret_cast<const float4*>(&logits[(i0 + ii) * 256 + j0]);
    const float4 b =
        *reinterpret_cast<const float4*>(&logits[(i0 + ii) * 256 + j0 + 4]);
    E[ii][0] = __expf(a.x);
    E[ii][1] = __expf(a.y);
    E[ii][2] = __expf(a.z);
    E[ii][3] = __expf(a.w);
    E[ii][4] = __expf(b.x);
    E[ii][5] = __expf(b.y);
    E[ii][6] = __expf(b.z);
    E[ii][7] = __expf(b.w);
  }
  __shared__ float part[32][8][32];
  __shared__ int partI[32][8][32];
  __shared__ float uu[256];
  __shared__ float vv[256];
  __shared__ int amax[256];
  if (tid < 256) uu[tid] = 1.f;
  __syncthreads();
  for (int it = 0; it < 20; ++it) {
    float ul[8];
#pragma unroll
    for (int ii = 0; ii < 8; ++ii) ul[ii] = uu[i0 + ii];
#pragma unroll
    for (int jj = 0; jj < 8; ++jj) {
      float s = 0.f;
#pragma unroll
      for (int ii = 0; ii < 8; ++ii) s += E[ii][jj] * ul[ii];
      part[ty][jj][tx] = s;
    }
    __syncthreads();
    if (tid < 256) {
      const int jj = tid >> 5, txr = tid & 31;
      float s = 0.f;
#pragma unroll
      for (int pp = 0; pp < 32; ++pp) s += part[pp][jj][txr];
      vv[txr * 8 + jj] = 1.f / s;
    }
    __syncthreads();
    float vl[8];
#pragma unroll
    for (int jj = 0; jj < 8; ++jj) vl[jj] = vv[j0 + jj];
#pragma unroll
    for (int ii = 0; ii < 8; ++ii) {
      float s = 0.f;
#pragma unroll
      for (int jj = 0; jj < 8; ++jj) s += E[ii][jj] * vl[jj];
      part[ty][ii][tx] = s;
    }
    __syncthreads();
    if (tid < 256) {
      const int i = tid;
      float s = 0.f;
#pragma unroll
      for (int pp = 0; pp < 32; ++pp) {
        const int pr = (pp + i) & 31;
        s += part[i >> 3][i & 7][pr];
      }
      uu[i] = 1.f / s;
    }
    __syncthreads();
  }
  float ul[8], vl[8];
#pragma unroll
  for (int ii = 0; ii < 8; ++ii) ul[ii] = uu[i0 + ii];
#pragma unroll
  for (int jj = 0; jj < 8; ++jj) vl[jj] = vv[j0 + jj];
#pragma unroll
  for (int ii = 0; ii < 8; ++ii) {
    float vals[8];
    float best = -1.f;
    int bidx = 0;
#pragma unroll
    for (int jj = 0; jj < 8; ++jj) {
      const float pv = E[ii][jj] * ul[ii] * vl[jj];
      vals[jj] = pv;
      if (pv > best) {
        best = pv;
        bidx = j0 + jj;
      }
    }
    *reinterpret_cast<float4*>(&out[(i0 + ii) * 256 + j0]) =
        make_float4(vals[0], vals[1], vals[2], vals[3]);
    *reinterpret_cast<float4*>(&out[(i0 + ii) * 256 + j0 + 4]) =
        make_float4(vals[4], vals[5], vals[6], vals[7]);
    part[ty][ii][tx] = best;
    partI[ty][ii][tx] = bidx;
  }
  __syncthreads();
  if (tid < 256) {
    const int i = tid;
    float best = -1.f;
    int bidx = 1 << 30;
#pragma unroll
    for (int pp = 0; pp < 32; ++pp) {
      const int pr = (pp + i) & 31;
      const float v = part[i >> 3][i & 7][pr];
      const int ix = partI[i >> 3][i & 7][pr];
      if (v > best || (v == best && ix < bidx)) {
        best = v;
        bidx = ix;
      }
    }
    amax[i] = bidx;
  }
  __syncthreads();
#pragma unroll
  for (int ii = 0; ii < 8; ++ii) {
    const int am = amax[i0 + ii];
    float4 h0, h1;
    h0.x = (j0 + 0 == am) ? 1.f : 0.f;
    h0.y = (j0 + 1 == am) ? 1.f : 0.f;
    h0.z = (j0 + 2 == am) ? 1.f : 0.f;
    h0.w = (j0 + 3 == am) ? 1.f : 0.f;
    h1.x = (j0 + 4 == am) ? 1.f : 0.f;
    h1.y = (j0 + 5 == am) ? 1.f : 0.f;
    h1.z = (j0 + 6 == am) ? 1.f : 0.f;
    h1.w = (j0 + 7 == am) ? 1.f : 0.f;
    *reinterpret_cast<float4*>(&out[65536 + (i0 + ii) * 256 + j0]) = h0;
    *reinterpret_cast<float4*>(&out[65536 + (i0 + ii) * 256 + j0 + 4]) = h1;
  }
}

// ---------------- host-side launch ------------------------------------------
extern "C" void kernel_launch(void* const* d_in, const int* in_sizes, int n_in,
                              void* d_out, int out_size, void* d_ws,
                              size_t ws_size, hipStream_t stream) {
  (void)in_sizes;
  (void)n_in;
  (void)out_size;
  (void)ws_size;
  MegaP p;
  p.in_x = (const float*)d_in[0];
  p.emb_w = (const float*)d_in[1];
  p.emb_b = (const float*)d_in[2];
  p.pos_emb = (const float*)d_in[3];
  p.cls_emb = (const float*)d_in[4];
  p.ipw = (const float*)d_in[5];
  p.ipb = (const float*)d_in[6];
  p.aow = (const float*)d_in[7];
  p.aob = (const float*)d_in[8];
  p.fw1 = (const float*)d_in[9];
  p.fb1 = (const float*)d_in[10];
  p.fw2 = (const float*)d_in[11];
  p.fb2 = (const float*)d_in[12];
  p.ln1g = (const float*)d_in[13];
  p.ln1b = (const float*)d_in[14];
  p.ln2g = (const float*)d_in[15];
  p.ln2b = (const float*)d_in[16];
  p.out_w = (const float*)d_in[17];
  p.out_b = (const float*)d_in[18];
  p.ws = (float*)d_ws;
  float* out = (float*)d_out;
  float* logits = p.ws + 1184256;

  void* kargs[] = {(void*)&p};
  hipError_t err =
      hipLaunchCooperativeKernel(mega, dim3(GRID_), dim3(NT_), kargs, 0,
                                 stream);
  if (err != hipSuccess) {
    (void)hipGetLastError();  // clear sticky error; use non-coop fallback
    phase_wrap<<<dim3(GRID_), dim3(NT_), 0, stream>>>(p, 0, 0);
    for (int l = 0; l < 4; ++l)
      for (int ph = 1; ph <= 9; ++ph)
        phase_wrap<<<dim3(GRID_), dim3(NT_), 0, stream>>>(p, ph, l);
    phase_wrap<<<dim3(GRID_), dim3(NT_), 0, stream>>>(p, 10, 0);
    phase_wrap<<<dim3(GRID_), dim3(NT_), 0, stream>>>(p, 11, 0);
  }
  sinkhorn_kernel<<<dim3(1), dim3(1024), 0, stream>>>(logits, out);
}

// Round 12
// 1777.806 us; speedup vs baseline: 1.4096x; 1.3760x over previous
//
#include <hip/hip_runtime.h>
#include <hip/hip_cooperative_groups.h>
#include <math.h>

namespace cg = cooperative_groups;

#define S_ 257
#define D_ 512
#define MB_ 5    // ceil(257/64)
#define GRID_ 256
#define NT_ 512  // 8 waves/block = 2 waves/SIMD at 1 block/CU

struct MegaP {
  const float* in_x;
  const float* emb_w;
  const float* emb_b;
  const float* pos_emb;
  const float* cls_emb;
  const float* ipw;
  const float* ipb;
  const float* aow;
  const float* aob;
  const float* fw1;
  const float* fb1;
  const float* fw2;
  const float* fb2;
  const float* ln1g;
  const float* ln1b;
  const float* ln2g;
  const float* ln2b;
  const float* out_w;
  const float* out_b;
  float* ws;
};

// Single-buffered tile: the reg-prefetch dbuf needed ~190 VGPRs, which is
// over the hard 128-VGPR cap of any >=2-waves/SIMD config (empirical law:
// cap = 256 / waves-per-SIMD; a 512-thread block implies >=2). r1's
// single-buffer datapath measured 44 VGPRs -> no spill at cap 128.
using Tile = float[32][68];

// ---- embed row job (uniform barrier structure incl. row 0) -----------------
__device__ __forceinline__ void embed_job(int row, bool active, int tid,
                                          const MegaP& p, float* sbuf) {
  float* src = p.ws;
  if (active && row > 0 && tid < 64) sbuf[tid] = p.in_x[(row - 1) * 64 + tid];
  __syncthreads();
  if (active) {
    for (int j = tid; j < D_; j += 256) {
      float v;
      if (row == 0) {
        v = p.cls_emb[j] + p.pos_emb[j];
      } else {
        float acc = p.emb_b[j];
#pragma unroll 8
        for (int k = 0; k < 64; ++k) acc += sbuf[k] * p.emb_w[k * D_ + j];
        v = acc + p.pos_emb[row * D_ + j];
      }
      src[row * D_ + j] = v;
    }
  }
  __syncthreads();
}

// ---- slim 64x64 single-buffer split-K GEMM, per 256-thread sub-block -------
template <bool TRANSB>
__device__ __forceinline__ void gemm_job(int job, bool active, int tid,
                                         const float* __restrict__ A,
                                         const float* __restrict__ B,
                                         float* __restrict__ out, int M, int N,
                                         int K, int kslice, int nb, int MNtot,
                                         Tile& As, Tile& Bs) {
  const int by = job % MB_;
  const int t2 = job / MB_;
  const int bx = t2 % nb;
  const int bz = t2 / nb;
  const int m0 = by * 64, n0 = bx * 64, kbeg = bz * kslice;

  const int sm = tid & 63;
  const int sk = (tid >> 6) * 8;
  const int bk = tid >> 3;
  const int bn = (tid & 7) * 8;

  float acc[4][4] = {};
  const int tx4 = (tid & 15) * 4;
  const int ty4 = (tid >> 4) * 4;
  const float4 z4 = make_float4(0.f, 0.f, 0.f, 0.f);

  const int nt = kslice >> 5;
  for (int t = 0; t < nt; ++t) {
    const int k0 = kbeg + t * 32;
    {  // stage A tile (transposed into [k][m])
      const int gm = m0 + sm;
      float4 ra0 = z4, ra1 = z4;
      if (gm < M) {
        const float* ptr = &A[(size_t)gm * K + k0 + sk];
        ra0 = *reinterpret_cast<const float4*>(ptr);
        ra1 = *reinterpret_cast<const float4*>(ptr + 4);
      }
      As[sk + 0][sm] = ra0.x;
      As[sk + 1][sm] = ra0.y;
      As[sk + 2][sm] = ra0.z;
      As[sk + 3][sm] = ra0.w;
      As[sk + 4][sm] = ra1.x;
      As[sk + 5][sm] = ra1.y;
      As[sk + 6][sm] = ra1.z;
      As[sk + 7][sm] = ra1.w;
      if (TRANSB) {
        const float* ptr = &B[(size_t)(n0 + sm) * K + k0 + sk];
        const float4 rb0 = *reinterpret_cast<const float4*>(ptr);
        const float4 rb1 = *reinterpret_cast<const float4*>(ptr + 4);
        Bs[sk + 0][sm] = rb0.x;
        Bs[sk + 1][sm] = rb0.y;
        Bs[sk + 2][sm] = rb0.z;
        Bs[sk + 3][sm] = rb0.w;
        Bs[sk + 4][sm] = rb1.x;
        Bs[sk + 5][sm] = rb1.y;
        Bs[sk + 6][sm] = rb1.z;
        Bs[sk + 7][sm] = rb1.w;
      } else {
        const float* ptr = &B[(size_t)(k0 + bk) * N + n0 + bn];
        *reinterpret_cast<float4*>(&Bs[bk][bn]) =
            *reinterpret_cast<const float4*>(ptr);
        *reinterpret_cast<float4*>(&Bs[bk][bn + 4]) =
            *reinterpret_cast<const float4*>(ptr + 4);
      }
    }
    __syncthreads();
#pragma unroll
    for (int k = 0; k < 32; ++k) {
      const float4 av = *reinterpret_cast<const float4*>(&As[k][ty4]);
      const float4 bv = *reinterpret_cast<const float4*>(&Bs[k][tx4]);
      acc[0][0] += av.x * bv.x;
      acc[0][1] += av.x * bv.y;
      acc[0][2] += av.x * bv.z;
      acc[0][3] += av.x * bv.w;
      acc[1][0] += av.y * bv.x;
      acc[1][1] += av.y * bv.y;
      acc[1][2] += av.y * bv.z;
      acc[1][3] += av.y * bv.w;
      acc[2][0] += av.z * bv.x;
      acc[2][1] += av.z * bv.y;
      acc[2][2] += av.z * bv.z;
      acc[2][3] += av.z * bv.w;
      acc[3][0] += av.w * bv.x;
      acc[3][1] += av.w * bv.y;
      acc[3][2] += av.w * bv.z;
      acc[3][3] += av.w * bv.w;
    }
    __syncthreads();
  }

  if (active) {
    float* pb = out + (size_t)bz * MNtot;
#pragma unroll
    for (int i = 0; i < 4; ++i) {
      const int m = m0 + ty4 + i;
      if (m >= M) break;
      *reinterpret_cast<float4*>(&pb[(size_t)m * N + n0 + tx4]) =
          make_float4(acc[i][0], acc[i][1], acc[i][2], acc[i][3]);
    }
  }
  __syncthreads();
}

// ---- attention job (one query row per 256-thread sub-block) ----------------
__device__ __forceinline__ void attn_job(int q, bool active, int tid,
                                         const float* __restrict__ qkv,
                                         float* __restrict__ attnO,
                                         float (*sc)[260], float (*qsh)[64]) {
  const int lane = tid & 31;
  const int hg = tid >> 5;
  {
    const int e = tid * 2;
    const float2 v =
        *reinterpret_cast<const float2*>(&qkv[(size_t)q * 1536 + e]);
    qsh[e >> 6][e & 63] = v.x;
    qsh[e >> 6][(e & 63) + 1] = v.y;
  }
  __syncthreads();
  float lm = -1e30f;
  for (int j = lane; j < S_; j += 32) {
    const float4* kr =
        reinterpret_cast<const float4*>(&qkv[(size_t)j * 1536 + 512 + hg * 64]);
    const float4* qr = reinterpret_cast<const float4*>(&qsh[hg][0]);
    float acc = 0.f;
#pragma unroll
    for (int d = 0; d < 16; ++d) {
      const float4 kk = kr[d], qq = qr[d];
      acc += kk.x * qq.x + kk.y * qq.y + kk.z * qq.z + kk.w * qq.w;
    }
    const float s = acc * 0.125f;
    sc[hg][j] = s;
    lm = fmaxf(lm, s);
  }
#pragma unroll
  for (int off = 16; off > 0; off >>= 1)
    lm = fmaxf(lm, __shfl_xor(lm, off, 32));
  float ls = 0.f;
  for (int j = lane; j < S_; j += 32) {
    const float pw = __expf(sc[hg][j] - lm);
    sc[hg][j] = pw;
    ls += pw;
  }
#pragma unroll
  for (int off = 16; off > 0; off >>= 1) ls += __shfl_xor(ls, off, 32);
  const float inv = 1.f / ls;
  __syncthreads();
  float a0 = 0.f, a1 = 0.f;
#pragma unroll 4
  for (int j = 0; j < S_; ++j) {
    const float pw = sc[hg][j];
    const float2 vv = *reinterpret_cast<const float2*>(
        &qkv[(size_t)j * 1536 + 1024 + hg * 64 + lane * 2]);
    a0 += pw * vv.x;
    a1 += pw * vv.y;
  }
  if (active)
    *reinterpret_cast<float2*>(&attnO[(size_t)q * D_ + hg * 64 + lane * 2]) =
        make_float2(a0 * inv, a1 * inv);
  __syncthreads();
}

// ---- split-K reduce + bias + residual + LayerNorm row job ------------------
__device__ __forceinline__ void ln_job(int row, bool active, int tid,
                                       const float* __restrict__ part, int S,
                                       const float* __restrict__ bias,
                                       float* __restrict__ io,
                                       const float* __restrict__ gg,
                                       const float* __restrict__ bb,
                                       float* redA, float* redB) {
  const size_t base = (size_t)row * D_;
  float x0 = io[base + tid] + bias[tid];
  float x1 = io[base + 256 + tid] + bias[256 + tid];
  for (int s = 0; s < S; ++s) {
    x0 += part[(size_t)s * (size_t)(S_ * D_) + base + tid];
    x1 += part[(size_t)s * (size_t)(S_ * D_) + base + 256 + tid];
  }
  float sm = x0 + x1;
#pragma unroll
  for (int off = 32; off > 0; off >>= 1) sm += __shfl_down(sm, off);
  if ((tid & 63) == 0) redA[tid >> 6] = sm;
  __syncthreads();
  const float mu = (redA[0] + redA[1] + redA[2] + redA[3]) * (1.f / 512.f);
  const float d0 = x0 - mu, d1 = x1 - mu;
  float qv = d0 * d0 + d1 * d1;
#pragma unroll
  for (int off = 32; off > 0; off >>= 1) qv += __shfl_down(qv, off);
  if ((tid & 63) == 0) redB[tid >> 6] = qv;
  __syncthreads();
  const float var = (redB[0] + redB[1] + redB[2] + redB[3]) * (1.f / 512.f);
  const float inv = rsqrtf(var + 1e-5f);
  if (active) {
    io[base + tid] = d0 * inv * gg[tid] + bb[tid];
    io[base + 256 + tid] = d1 * inv * gg[256 + tid] + bb[256 + tid];
  }
  __syncthreads();
}

// ---- head gemv job ---------------------------------------------------------
__device__ __forceinline__ void gemv_job(int job, int tid,
                                         const float* __restrict__ src,
                                         const float* __restrict__ out_w,
                                         float* __restrict__ part,
                                         float* __restrict__ sbuf) {
  const int jc = job & 63;
  const int dc = job >> 6;
  if (tid < 64) sbuf[tid] = src[dc * 64 + tid];
  __syncthreads();
  const int j0 = jc * 1024 + tid * 4;
  float4 acc = make_float4(0.f, 0.f, 0.f, 0.f);
  for (int d = 0; d < 64; ++d) {
    const float sv = sbuf[d];
    const float4 w = *reinterpret_cast<const float4*>(
        &out_w[(size_t)(dc * 64 + d) * 65536 + j0]);
    acc.x += sv * w.x;
    acc.y += sv * w.y;
    acc.z += sv * w.z;
    acc.w += sv * w.w;
  }
  *reinterpret_cast<float4*>(&part[(size_t)dc * 65536 + j0]) = acc;
  __syncthreads();
}

// ---- barrier-free grid-stride reduce (+bias, opt relu) ---------------------
__device__ __forceinline__ void reduce_phase(int bid, int tid512,
                                             const float* __restrict__ part,
                                             const float* __restrict__ bias,
                                             float* __restrict__ out, int MN4,
                                             int N4, int S, int relu) {
  for (int i = bid * NT_ + tid512; i < MN4; i += GRID_ * NT_) {
    float4 acc = reinterpret_cast<const float4*>(bias)[i % N4];
    for (int s = 0; s < S; ++s) {
      const float4 v =
          reinterpret_cast<const float4*>(part)[(size_t)s * MN4 + i];
      acc.x += v.x;
      acc.y += v.y;
      acc.z += v.z;
      acc.w += v.w;
    }
    if (relu) {
      acc.x = fmaxf(acc.x, 0.f);
      acc.y = fmaxf(acc.y, 0.f);
      acc.z = fmaxf(acc.z, 0.f);
      acc.w = fmaxf(acc.w, 0.f);
    }
    reinterpret_cast<float4*>(out)[i] = acc;
  }
}

// ---- one phase of the pipeline (shared by mega and fallback wrapper) -------
__device__ __forceinline__ void run_phase(int phase, int l, const MegaP& p,
                                          int bid, int g, int tid, int tid512,
                                          Tile& As, Tile& Bs, float (*sc)[260],
                                          float (*qsh)[64], float* redA,
                                          float* redB, float* sbuf) {
  float* ws = p.ws;
  float* src = ws;               // 257*512
  float* qkv = ws + 131584;      // 257*1536
  float* attnO = ws + 526336;    // 257*512
  float* ffh = ws + 657920;      // 257*2048
  float* logits = ws + 1184256;  // 65536
  float* part = ws + 1249792;    // up to 4*394752
  const int jr = bid * 2 + g;    // sub-block job slot (uniform per sub-block)
  switch (phase) {
    case 0: {
      const bool a = jr < S_;
      embed_job(a ? jr : S_ - 1, a, tid, p, sbuf);
    } break;
    case 1: {  // qkv partials: splitK4, 480 jobs, nt=4
      const bool a = jr < 480;
      gemm_job<true>(a ? jr : 479, a, tid, src,
                     p.ipw + (size_t)l * 1536 * 512, part, S_, 1536, 512, 128,
                     24, S_ * 1536, As, Bs);
    } break;
    case 2:  // qkv reduce + bias
      reduce_phase(bid, tid512, part, p.ipb + l * 1536, qkv, (S_ * 1536) / 4,
                   384, 4, 0);
      break;
    case 3: {
      const bool a = jr < S_;
      attn_job(a ? jr : S_ - 1, a, tid, qkv, attnO, sc, qsh);
    } break;
    case 4: {  // proj partials: splitK8, 320 jobs, nt=2
      const bool a = jr < 320;
      gemm_job<true>(a ? jr : 319, a, tid, attnO,
                     p.aow + (size_t)l * 512 * 512, part, S_, 512, 512, 64, 8,
                     S_ * D_, As, Bs);
    } break;
    case 5: {
      const bool a = jr < S_;
      ln_job(a ? jr : S_ - 1, a, tid, part, 8, p.aob + l * 512, src,
             p.ln1g + l * 512, p.ln1b + l * 512, redA, redB);
    } break;
    case 6: {  // ff1 partials: splitK2, 320 jobs, nt=8
      const bool a = jr < 320;
      gemm_job<false>(a ? jr : 319, a, tid, src,
                      p.fw1 + (size_t)l * 512 * 2048, part, S_, 2048, 512, 256,
                      32, S_ * 2048, As, Bs);
    } break;
    case 7:  // ff1 reduce + bias + relu
      reduce_phase(bid, tid512, part, p.fb1 + l * 2048, ffh, (S_ * 2048) / 4,
                   512, 2, 1);
      break;
    case 8: {  // ff2 partials: splitK8, 320 jobs, nt=8
      const bool a = jr < 320;
      gemm_job<false>(a ? jr : 319, a, tid, ffh,
                      p.fw2 + (size_t)l * 2048 * 512, part, S_, 512, 2048, 256,
                      8, S_ * D_, As, Bs);
    } break;
    case 9: {
      const bool a = jr < S_;
      ln_job(a ? jr : S_ - 1, a, tid, part, 8, p.fb2 + l * 512, src,
             p.ln2g + l * 512, p.ln2b + l * 512, redA, redB);
    } break;
    case 10:  // head gemv: 512 jobs
      gemv_job(jr, tid, src, p.out_w, part, sbuf);
      break;
    case 11:  // logits = sum(8 parts) + out_b
      reduce_phase(bid, tid512, part, p.out_b, logits, 16384, 16384, 8, 0);
      break;
  }
}

// ---- the megakernel: 512 threads = two 256-thread sub-blocks ---------------
__global__ __launch_bounds__(NT_, 1) void mega(MegaP p) {
  cg::grid_group grid = cg::this_grid();
  const int bid = blockIdx.x;
  const int tid512 = threadIdx.x;
  const int g = tid512 >> 8;
  const int tid = tid512 & 255;

  __shared__ __align__(16) float As[2][32][68];
  __shared__ __align__(16) float Bs[2][32][68];
  __shared__ __align__(16) float sc[2][8][260];
  __shared__ __align__(16) float qsh[2][8][64];
  __shared__ float redA[2][4], redB[2][4];
  __shared__ __align__(16) float sbuf[2][64];

  run_phase(0, 0, p, bid, g, tid, tid512, As[g], Bs[g], sc[g], qsh[g], redA[g],
            redB[g], sbuf[g]);
  grid.sync();
  for (int l = 0; l < 4; ++l) {
    for (int ph = 1; ph <= 9; ++ph) {
      run_phase(ph, l, p, bid, g, tid, tid512, As[g], Bs[g], sc[g], qsh[g],
                redA[g], redB[g], sbuf[g]);
      grid.sync();
    }
  }
  run_phase(10, 0, p, bid, g, tid, tid512, As[g], Bs[g], sc[g], qsh[g],
            redA[g], redB[g], sbuf[g]);
  grid.sync();
  run_phase(11, 0, p, bid, g, tid, tid512, As[g], Bs[g], sc[g], qsh[g],
            redA[g], redB[g], sbuf[g]);
}

// ---- fallback: one phase per launch, same code path ------------------------
__global__ __launch_bounds__(NT_, 1) void phase_wrap(MegaP p, int phase,
                                                     int l) {
  const int bid = blockIdx.x;
  const int tid512 = threadIdx.x;
  const int g = tid512 >> 8;
  const int tid = tid512 & 255;
  __shared__ __align__(16) float As[2][32][68];
  __shared__ __align__(16) float Bs[2][32][68];
  __shared__ __align__(16) float sc[2][8][260];
  __shared__ __align__(16) float qsh[2][8][64];
  __shared__ float redA[2][4], redB[2][4];
  __shared__ __align__(16) float sbuf[2][64];
  run_phase(phase, l, p, bid, g, tid, tid512, As[g], Bs[g], sc[g], qsh[g],
            redA[g], redB[g], sbuf[g]);
}

// ---------------- sinkhorn (rank-1 reformulation, unchanged) ----------------
__global__ __launch_bounds__(1024) void sinkhorn_kernel(
    const float* __restrict__ logits, float* __restrict__ out) {
  const int tid = threadIdx.x;
  const int tx = tid & 31;
  const int ty = tid >> 5;
  const int i0 = ty * 8, j0 = tx * 8;
  float E[8][8];
#pragma unroll
  for (int ii = 0; ii < 8; ++ii) {
    const float4 a =
        *reinterpret_cast<const float4*>(&logits[(i0 + ii) * 256 + j0]);
    const float4 b =
        *reinterpret_cast<const float4*>(&logits[(i0 + ii) * 256 + j0 + 4]);
    E[ii][0] = __expf(a.x);
    E[ii][1] = __expf(a.y);
    E[ii][2] = __expf(a.z);
    E[ii][3] = __expf(a.w);
    E[ii][4] = __expf(b.x);
    E[ii][5] = __expf(b.y);
    E[ii][6] = __expf(b.z);
    E[ii][7] = __expf(b.w);
  }
  __shared__ float part[32][8][32];
  __shared__ int partI[32][8][32];
  __shared__ float uu[256];
  __shared__ float vv[256];
  __shared__ int amax[256];
  if (tid < 256) uu[tid] = 1.f;
  __syncthreads();
  for (int it = 0; it < 20; ++it) {
    float ul[8];
#pragma unroll
    for (int ii = 0; ii < 8; ++ii) ul[ii] = uu[i0 + ii];
#pragma unroll
    for (int jj = 0; jj < 8; ++jj) {
      float s = 0.f;
#pragma unroll
      for (int ii = 0; ii < 8; ++ii) s += E[ii][jj] * ul[ii];
      part[ty][jj][tx] = s;
    }
    __syncthreads();
    if (tid < 256) {
      const int jj = tid >> 5, txr = tid & 31;
      float s = 0.f;
#pragma unroll
      for (int pp = 0; pp < 32; ++pp) s += part[pp][jj][txr];
      vv[txr * 8 + jj] = 1.f / s;
    }
    __syncthreads();
    float vl[8];
#pragma unroll
    for (int jj = 0; jj < 8; ++jj) vl[jj] = vv[j0 + jj];
#pragma unroll
    for (int ii = 0; ii < 8; ++ii) {
      float s = 0.f;
#pragma unroll
      for (int jj = 0; jj < 8; ++jj) s += E[ii][jj] * vl[jj];
      part[ty][ii][tx] = s;
    }
    __syncthreads();
    if (tid < 256) {
      const int i = tid;
      float s = 0.f;
#pragma unroll
      for (int pp = 0; pp < 32; ++pp) {
        const int pr = (pp + i) & 31;
        s += part[i >> 3][i & 7][pr];
      }
      uu[i] = 1.f / s;
    }
    __syncthreads();
  }
  float ul[8], vl[8];
#pragma unroll
  for (int ii = 0; ii < 8; ++ii) ul[ii] = uu[i0 + ii];
#pragma unroll
  for (int jj = 0; jj < 8; ++jj) vl[jj] = vv[j0 + jj];
#pragma unroll
  for (int ii = 0; ii < 8; ++ii) {
    float vals[8];
    float best = -1.f;
    int bidx = 0;
#pragma unroll
    for (int jj = 0; jj < 8; ++jj) {
      const float pv = E[ii][jj] * ul[ii] * vl[jj];
      vals[jj] = pv;
      if (pv > best) {
        best = pv;
        bidx = j0 + jj;
      }
    }
    *reinterpret_cast<float4*>(&out[(i0 + ii) * 256 + j0]) =
        make_float4(vals[0], vals[1], vals[2], vals[3]);
    *reinterpret_cast<float4*>(&out[(i0 + ii) * 256 + j0 + 4]) =
        make_float4(vals[4], vals[5], vals[6], vals[7]);
    part[ty][ii][tx] = best;
    partI[ty][ii][tx] = bidx;
  }
  __syncthreads();
  if (tid < 256) {
    const int i = tid;
    float best = -1.f;
    int bidx = 1 << 30;
#pragma unroll
    for (int pp = 0; pp < 32; ++pp) {
      const int pr = (pp + i) & 31;
      const float v = part[i >> 3][i & 7][pr];
      const int ix = partI[i >> 3][i & 7][pr];
      if (v > best || (v == best && ix < bidx)) {
        best = v;
        bidx = ix;
      }
    }
    amax[i] = bidx;
  }
  __syncthreads();
#pragma unroll
  for (int ii = 0; ii < 8; ++ii) {
    const int am = amax[i0 + ii];
    float4 h0, h1;
    h0.x = (j0 + 0 == am) ? 1.f : 0.f;
    h0.y = (j0 + 1 == am) ? 1.f : 0.f;
    h0.z = (j0 + 2 == am) ? 1.f : 0.f;
    h0.w = (j0 + 3 == am) ? 1.f : 0.f;
    h1.x = (j0 + 4 == am) ? 1.f : 0.f;
    h1.y = (j0 + 5 == am) ? 1.f : 0.f;
    h1.z = (j0 + 6 == am) ? 1.f : 0.f;
    h1.w = (j0 + 7 == am) ? 1.f : 0.f;
    *reinterpret_cast<float4*>(&out[65536 + (i0 + ii) * 256 + j0]) = h0;
    *reinterpret_cast<float4*>(&out[65536 + (i0 + ii) * 256 + j0 + 4]) = h1;
  }
}

// ---------------- host-side launch ------------------------------------------
extern "C" void kernel_launch(void* const* d_in, const int* in_sizes, int n_in,
                              void* d_out, int out_size, void* d_ws,
                              size_t ws_size, hipStream_t stream) {
  (void)in_sizes;
  (void)n_in;
  (void)out_size;
  (void)ws_size;
  MegaP p;
  p.in_x = (const float*)d_in[0];
  p.emb_w = (const float*)d_in[1];
  p.emb_b = (const float*)d_in[2];
  p.pos_emb = (const float*)d_in[3];
  p.cls_emb = (const float*)d_in[4];
  p.ipw = (const float*)d_in[5];
  p.ipb = (const float*)d_in[6];
  p.aow = (const float*)d_in[7];
  p.aob = (const float*)d_in[8];
  p.fw1 = (const float*)d_in[9];
  p.fb1 = (const float*)d_in[10];
  p.fw2 = (const float*)d_in[11];
  p.fb2 = (const float*)d_in[12];
  p.ln1g = (const float*)d_in[13];
  p.ln1b = (const float*)d_in[14];
  p.ln2g = (const float*)d_in[15];
  p.ln2b = (const float*)d_in[16];
  p.out_w = (const float*)d_in[17];
  p.out_b = (const float*)d_in[18];
  p.ws = (float*)d_ws;
  float* out = (float*)d_out;
  float* logits = p.ws + 1184256;

  void* kargs[] = {(void*)&p};
  hipError_t err =
      hipLaunchCooperativeKernel(mega, dim3(GRID_), dim3(NT_), kargs, 0,
                                 stream);
  if (err != hipSuccess) {
    (void)hipGetLastError();  // clear sticky error; use non-coop fallback
    phase_wrap<<<dim3(GRID_), dim3(NT_), 0, stream>>>(p, 0, 0);
    for (int l = 0; l < 4; ++l)
      for (int ph = 1; ph <= 9; ++ph)
        phase_wrap<<<dim3(GRID_), dim3(NT_), 0, stream>>>(p, ph, l);
    phase_wrap<<<dim3(GRID_), dim3(NT_), 0, stream>>>(p, 10, 0);
    phase_wrap<<<dim3(GRID_), dim3(NT_), 0, stream>>>(p, 11, 0);
  }
  sinkhorn_kernel<<<dim3(1), dim3(1024), 0, stream>>>(logits, out);
}

// Round 13
// 606.141 us; speedup vs baseline: 4.1344x; 2.9330x over previous
//
#include <hip/hip_runtime.h>
#include <math.h>

#define S_ 257
#define D_ 512
#define MB_ 5  // ceil(257/64)

typedef __attribute__((ext_vector_type(8))) short bf16x8;
typedef __attribute__((ext_vector_type(4))) float f32x4;

__device__ __forceinline__ unsigned pack2(unsigned short a, unsigned short b) {
  return (unsigned)a | ((unsigned)b << 16);
}
__device__ __forceinline__ void split_hl(float x, unsigned short& h,
                                         unsigned short& l) {
  const unsigned u = __float_as_uint(x);
  h = (unsigned short)(u >> 16);
  const float xh = __uint_as_float(u & 0xFFFF0000u);
  l = (unsigned short)(__float_as_uint(x - xh) >> 16);
}

// ---------------- embed ------------------------------------------------------
__global__ __launch_bounds__(256) void embed_kernel(
    const float* __restrict__ in_x, const float* __restrict__ emb_w,
    const float* __restrict__ emb_b, const float* __restrict__ pos_emb,
    const float* __restrict__ cls_emb, float* __restrict__ src) {
  const int row = blockIdx.x;
  const int tid = threadIdx.x;
  if (row == 0) {
    for (int j = tid; j < D_; j += 256) src[j] = cls_emb[j] + pos_emb[j];
    return;
  }
  __shared__ __align__(16) float xr[64];
  if (tid < 64) xr[tid] = in_x[(row - 1) * 64 + tid];
  __syncthreads();
  for (int j = tid; j < D_; j += 256) {
    float acc = emb_b[j];
#pragma unroll 8
    for (int k = 0; k < 64; ++k) acc += xr[k] * emb_w[k * D_ + j];
    src[row * D_ + j] = acc + pos_emb[row * D_ + j];
  }
}

// ---------------- MFMA split-K GEMM, 64x64 tile, hi/lo bf16 ------------------
// part[bz][m][n] = sum_{k in slice} A[m,k]*(TRANSB ? B[n,k] : B[k,n])
template <bool TRANSB>
__global__ __launch_bounds__(256, 2) void gemm_mfma(
    const float* __restrict__ A, const float* __restrict__ B,
    float* __restrict__ part, int M, int N, int K, int kslice, int nb,
    int MNtot) {
  // bijective XCD swizzle (grids are multiples of 8)
  const int q = gridDim.x >> 3;
  const int orig = blockIdx.x;
  const int logical = (orig & 7) * q + (orig >> 3);
  const int by = logical % MB_;  // m fastest: same-XCD blocks share B panel
  const int t2 = logical / MB_;
  const int bx = t2 % nb;
  const int bz = t2 / nb;
  const int m0 = by * 64, n0 = bx * 64, kbeg = bz * kslice;

  __shared__ __align__(16) unsigned short Ah[64][40];
  __shared__ __align__(16) unsigned short Al[64][40];
  __shared__ __align__(16) unsigned short Bh[64][40];
  __shared__ __align__(16) unsigned short Bl[64][40];

  const int tid = threadIdx.x;
  const int sm = tid & 63;        // staged row (A: m, B^T: n)
  const int sk = (tid >> 6) * 8;  // k offset {0,8,16,24}
  const int bk = tid >> 3;        // non-TRANSB: k row 0..31
  const int bn = (tid & 7) * 8;   // non-TRANSB: n offset

  const int lane = tid & 63;
  const int wave = tid >> 6;
  const int wr = wave >> 1;  // wave's 32-row half
  const int wc = wave & 1;   // wave's 32-col half
  const int fr = lane & 15;  // fragment row/col index
  const int ko = (lane >> 4) * 8;

  const f32x4 zf = {0.f, 0.f, 0.f, 0.f};
  f32x4 acc[2][2] = {{zf, zf}, {zf, zf}};

  const int nt = kslice >> 5;
  for (int t = 0; t < nt; ++t) {
    const int k0 = kbeg + t * 32;
    {  // stage A (hi/lo bf16, [m][k] layout)
      float f[8];
      const int gm = m0 + sm;
      if (gm < M) {
        const float4 a0 = *reinterpret_cast<const float4*>(
            &A[(size_t)gm * K + k0 + sk]);
        const float4 a1 = *reinterpret_cast<const float4*>(
            &A[(size_t)gm * K + k0 + sk + 4]);
        f[0] = a0.x; f[1] = a0.y; f[2] = a0.z; f[3] = a0.w;
        f[4] = a1.x; f[5] = a1.y; f[6] = a1.z; f[7] = a1.w;
      } else {
#pragma unroll
        for (int i = 0; i < 8; ++i) f[i] = 0.f;
      }
      unsigned short h[8], l[8];
#pragma unroll
      for (int i = 0; i < 8; ++i) split_hl(f[i], h[i], l[i]);
      *reinterpret_cast<uint4*>(&Ah[sm][sk]) =
          make_uint4(pack2(h[0], h[1]), pack2(h[2], h[3]), pack2(h[4], h[5]),
                     pack2(h[6], h[7]));
      *reinterpret_cast<uint4*>(&Al[sm][sk]) =
          make_uint4(pack2(l[0], l[1]), pack2(l[2], l[3]), pack2(l[4], l[5]),
                     pack2(l[6], l[7]));
    }
    if (TRANSB) {  // B is (N,K): same pattern as A
      const float4 b0 = *reinterpret_cast<const float4*>(
          &B[(size_t)(n0 + sm) * K + k0 + sk]);
      const float4 b1 = *reinterpret_cast<const float4*>(
          &B[(size_t)(n0 + sm) * K + k0 + sk + 4]);
      float f[8] = {b0.x, b0.y, b0.z, b0.w, b1.x, b1.y, b1.z, b1.w};
      unsigned short h[8], l[8];
#pragma unroll
      for (int i = 0; i < 8; ++i) split_hl(f[i], h[i], l[i]);
      *reinterpret_cast<uint4*>(&Bh[sm][sk]) =
          make_uint4(pack2(h[0], h[1]), pack2(h[2], h[3]), pack2(h[4], h[5]),
                     pack2(h[6], h[7]));
      *reinterpret_cast<uint4*>(&Bl[sm][sk]) =
          make_uint4(pack2(l[0], l[1]), pack2(l[2], l[3]), pack2(l[4], l[5]),
                     pack2(l[6], l[7]));
    } else {  // B is (K,N): transpose into [n][k] via scalar writes
      const float4 b0 = *reinterpret_cast<const float4*>(
          &B[(size_t)(k0 + bk) * N + n0 + bn]);
      const float4 b1 = *reinterpret_cast<const float4*>(
          &B[(size_t)(k0 + bk) * N + n0 + bn + 4]);
      const float f[8] = {b0.x, b0.y, b0.z, b0.w, b1.x, b1.y, b1.z, b1.w};
#pragma unroll
      for (int i = 0; i < 8; ++i) {
        unsigned short h, l;
        split_hl(f[i], h, l);
        Bh[bn + i][bk] = h;
        Bl[bn + i][bk] = l;
      }
    }
    __syncthreads();
    // fragment loads + 12 MFMA (hi*hi + hi*lo + lo*hi)
    bf16x8 ah[2], al_[2], bh[2], bl_[2];
#pragma unroll
    for (int mf = 0; mf < 2; ++mf) {
      ah[mf] = *reinterpret_cast<const bf16x8*>(&Ah[wr * 32 + mf * 16 + fr][ko]);
      al_[mf] =
          *reinterpret_cast<const bf16x8*>(&Al[wr * 32 + mf * 16 + fr][ko]);
      bh[mf] = *reinterpret_cast<const bf16x8*>(&Bh[wc * 32 + mf * 16 + fr][ko]);
      bl_[mf] =
          *reinterpret_cast<const bf16x8*>(&Bl[wc * 32 + mf * 16 + fr][ko]);
    }
#pragma unroll
    for (int mf = 0; mf < 2; ++mf)
#pragma unroll
      for (int nf = 0; nf < 2; ++nf) {
        acc[mf][nf] = __builtin_amdgcn_mfma_f32_16x16x32_bf16(
            ah[mf], bh[nf], acc[mf][nf], 0, 0, 0);
        acc[mf][nf] = __builtin_amdgcn_mfma_f32_16x16x32_bf16(
            ah[mf], bl_[nf], acc[mf][nf], 0, 0, 0);
        acc[mf][nf] = __builtin_amdgcn_mfma_f32_16x16x32_bf16(
            al_[mf], bh[nf], acc[mf][nf], 0, 0, 0);
      }
    __syncthreads();
  }

  // C-write: D layout col=lane&15, row=(lane>>4)*4+j  [verified m89/m91]
  float* pb = part + (size_t)bz * MNtot;
#pragma unroll
  for (int mf = 0; mf < 2; ++mf)
#pragma unroll
    for (int nf = 0; nf < 2; ++nf) {
      const int n = n0 + wc * 32 + nf * 16 + fr;
#pragma unroll
      for (int j = 0; j < 4; ++j) {
        const int m = m0 + wr * 32 + mf * 16 + (lane >> 4) * 4 + j;
        if (m < M) pb[(size_t)m * N + n] = acc[mf][nf][j];
      }
    }
}

// ---------------- split-K reduce: + bias (+relu), elementwise ---------------
__global__ __launch_bounds__(256) void reduce_elem(const float* __restrict__ part,
                                                   const float* __restrict__ bias,
                                                   float* __restrict__ out,
                                                   int MN, int N, int S,
                                                   int relu) {
  const int i = (blockIdx.x * 256 + threadIdx.x) * 4;
  if (i >= MN) return;
  const float4 bb = *reinterpret_cast<const float4*>(&bias[i % N]);
  float4 acc = bb;
  for (int s = 0; s < S; ++s) {
    const float4 v = *reinterpret_cast<const float4*>(&part[(size_t)s * MN + i]);
    acc.x += v.x;
    acc.y += v.y;
    acc.z += v.z;
    acc.w += v.w;
  }
  if (relu) {
    acc.x = fmaxf(acc.x, 0.f);
    acc.y = fmaxf(acc.y, 0.f);
    acc.z = fmaxf(acc.z, 0.f);
    acc.w = fmaxf(acc.w, 0.f);
  }
  *reinterpret_cast<float4*>(&out[i]) = acc;
}

// ---------------- split-K reduce + bias + residual + LayerNorm --------------
__global__ __launch_bounds__(256) void reduce_ln(const float* __restrict__ part,
                                                 const float* __restrict__ bias,
                                                 float* __restrict__ io,
                                                 const float* __restrict__ g,
                                                 const float* __restrict__ b,
                                                 int S) {
  const int row = blockIdx.x;
  const int tid = threadIdx.x;
  const size_t base = (size_t)row * D_;
  float x0 = io[base + tid] + bias[tid];
  float x1 = io[base + 256 + tid] + bias[256 + tid];
  for (int s = 0; s < S; ++s) {
    x0 += part[(size_t)s * (S_ * D_) + base + tid];
    x1 += part[(size_t)s * (S_ * D_) + base + 256 + tid];
  }
  __shared__ float redA[4], redB[4];
  float s = x0 + x1;
#pragma unroll
  for (int off = 32; off > 0; off >>= 1) s += __shfl_down(s, off);
  if ((tid & 63) == 0) redA[tid >> 6] = s;
  __syncthreads();
  const float mu = (redA[0] + redA[1] + redA[2] + redA[3]) * (1.f / 512.f);
  const float d0 = x0 - mu, d1 = x1 - mu;
  float qv = d0 * d0 + d1 * d1;
#pragma unroll
  for (int off = 32; off > 0; off >>= 1) qv += __shfl_down(qv, off);
  if ((tid & 63) == 0) redB[tid >> 6] = qv;
  __syncthreads();
  const float var = (redB[0] + redB[1] + redB[2] + redB[3]) * (1.f / 512.f);
  const float inv = rsqrtf(var + 1e-5f);
  io[base + tid] = d0 * inv * g[tid] + b[tid];
  io[base + 256 + tid] = d1 * inv * g[256 + tid] + b[256 + tid];
}

// ---------------- attention (one block per (query, head)) ------------------
__global__ __launch_bounds__(256) void attn_kernel(const float* __restrict__ qkv,
                                                   float* __restrict__ o) {
  const int sq = blockIdx.x;
  const int h = blockIdx.y;
  const int tid = threadIdx.x;
  __shared__ __align__(16) float qv[64];
  __shared__ float sc[S_];
  __shared__ float redA[4], redB[4];
  __shared__ float pv[4][64];
  if (tid < 64) qv[tid] = qkv[(size_t)sq * 1536 + h * 64 + tid];
  __syncthreads();
  for (int j = tid; j < S_; j += 256) {
    const float4* kr =
        reinterpret_cast<const float4*>(&qkv[(size_t)j * 1536 + D_ + h * 64]);
    const float4* qr = reinterpret_cast<const float4*>(qv);
    float acc = 0.f;
#pragma unroll
    for (int d = 0; d < 16; ++d) {
      const float4 kk = kr[d], qq = qr[d];
      acc += kk.x * qq.x + kk.y * qq.y + kk.z * qq.z + kk.w * qq.w;
    }
    sc[j] = acc * 0.125f;
  }
  __syncthreads();
  float lm = -1e30f;
  for (int j = tid; j < S_; j += 256) lm = fmaxf(lm, sc[j]);
#pragma unroll
  for (int off = 32; off > 0; off >>= 1) lm = fmaxf(lm, __shfl_down(lm, off));
  if ((tid & 63) == 0) redA[tid >> 6] = lm;
  __syncthreads();
  const float M = fmaxf(fmaxf(redA[0], redA[1]), fmaxf(redA[2], redA[3]));
  float ls = 0.f;
  for (int j = tid; j < S_; j += 256) {
    const float p = __expf(sc[j] - M);
    sc[j] = p;
    ls += p;
  }
#pragma unroll
  for (int off = 32; off > 0; off >>= 1) ls += __shfl_down(ls, off);
  if ((tid & 63) == 0) redB[tid >> 6] = ls;
  __syncthreads();
  const float invS = 1.f / (redB[0] + redB[1] + redB[2] + redB[3]);
  const int d = tid & 63;
  const int ch = tid >> 6;
  float acc = 0.f;
  for (int j = ch; j < S_; j += 4)
    acc += sc[j] * qkv[(size_t)j * 1536 + 2 * D_ + h * 64 + d];
  pv[ch][d] = acc;
  __syncthreads();
  if (tid < 64)
    o[(size_t)sq * D_ + h * 64 + tid] =
        (pv[0][tid] + pv[1][tid] + pv[2][tid] + pv[3][tid]) * invS;
}

// ---------------- output head GEMV (split-d partials) -----------------------
__global__ __launch_bounds__(256) void gemv_kernel(const float* __restrict__ src0,
                                                   const float* __restrict__ out_w,
                                                   float* __restrict__ parts) {
  const int jc = blockIdx.x;
  const int dc = blockIdx.y;
  const int tid = threadIdx.x;
  __shared__ __align__(16) float s0[64];
  if (tid < 64) s0[tid] = src0[dc * 64 + tid];
  __syncthreads();
  const int j0 = jc * 1024 + tid * 4;
  float4 acc = make_float4(0.f, 0.f, 0.f, 0.f);
  for (int d = 0; d < 64; ++d) {
    const float sv = s0[d];
    const float4 w = *reinterpret_cast<const float4*>(
        &out_w[(size_t)(dc * 64 + d) * 65536 + j0]);
    acc.x += sv * w.x;
    acc.y += sv * w.y;
    acc.z += sv * w.z;
    acc.w += sv * w.w;
  }
  *reinterpret_cast<float4*>(&parts[(size_t)dc * 65536 + j0]) = acc;
}

__global__ __launch_bounds__(256) void logits_reduce_kernel(
    const float* __restrict__ parts, const float* __restrict__ out_b,
    float* __restrict__ logits) {
  const int j = (blockIdx.x * 256 + threadIdx.x) * 4;
  float4 acc = *reinterpret_cast<const float4*>(&out_b[j]);
#pragma unroll
  for (int p = 0; p < 8; ++p) {
    const float4 v =
        *reinterpret_cast<const float4*>(&parts[(size_t)p * 65536 + j]);
    acc.x += v.x;
    acc.y += v.y;
    acc.z += v.z;
    acc.w += v.w;
  }
  *reinterpret_cast<float4*>(&logits[j]) = acc;
}

// ---------------- sinkhorn (rank-1 reformulation) ---------------------------
__global__ __launch_bounds__(1024) void sinkhorn_kernel(
    const float* __restrict__ logits, float* __restrict__ out) {
  const int tid = threadIdx.x;
  const int tx = tid & 31;
  const int ty = tid >> 5;
  const int i0 = ty * 8, j0 = tx * 8;
  float E[8][8];
#pragma unroll
  for (int ii = 0; ii < 8; ++ii) {
    const float4 a =
        *reinterpret_cast<const float4*>(&logits[(i0 + ii) * 256 + j0]);
    const float4 b =
        *reinterpret_cast<const float4*>(&logits[(i0 + ii) * 256 + j0 + 4]);
    E[ii][0] = __expf(a.x);
    E[ii][1] = __expf(a.y);
    E[ii][2] = __expf(a.z);
    E[ii][3] = __expf(a.w);
    E[ii][4] = __expf(b.x);
    E[ii][5] = __expf(b.y);
    E[ii][6] = __expf(b.z);
    E[ii][7] = __expf(b.w);
  }
  __shared__ float part[32][8][32];
  __shared__ int partI[32][8][32];
  __shared__ float uu[256];
  __shared__ float vv[256];
  __shared__ int amax[256];
  if (tid < 256) uu[tid] = 1.f;
  __syncthreads();
  for (int it = 0; it < 20; ++it) {
    float ul[8];
#pragma unroll
    for (int ii = 0; ii < 8; ++ii) ul[ii] = uu[i0 + ii];
#pragma unroll
    for (int jj = 0; jj < 8; ++jj) {
      float s = 0.f;
#pragma unroll
      for (int ii = 0; ii < 8; ++ii) s += E[ii][jj] * ul[ii];
      part[ty][jj][tx] = s;
    }
    __syncthreads();
    if (tid < 256) {
      const int jj = tid >> 5, txr = tid & 31;
      float s = 0.f;
#pragma unroll
      for (int pp = 0; pp < 32; ++pp) s += part[pp][jj][txr];
      vv[txr * 8 + jj] = 1.f / s;
    }
    __syncthreads();
    float vl[8];
#pragma unroll
    for (int jj = 0; jj < 8; ++jj) vl[jj] = vv[j0 + jj];
#pragma unroll
    for (int ii = 0; ii < 8; ++ii) {
      float s = 0.f;
#pragma unroll
      for (int jj = 0; jj < 8; ++jj) s += E[ii][jj] * vl[jj];
      part[ty][ii][tx] = s;
    }
    __syncthreads();
    if (tid < 256) {
      const int i = tid;
      float s = 0.f;
#pragma unroll
      for (int pp = 0; pp < 32; ++pp) {
        const int pr = (pp + i) & 31;
        s += part[i >> 3][i & 7][pr];
      }
      uu[i] = 1.f / s;
    }
    __syncthreads();
  }
  float ul[8], vl[8];
#pragma unroll
  for (int ii = 0; ii < 8; ++ii) ul[ii] = uu[i0 + ii];
#pragma unroll
  for (int jj = 0; jj < 8; ++jj) vl[jj] = vv[j0 + jj];
#pragma unroll
  for (int ii = 0; ii < 8; ++ii) {
    float vals[8];
    float best = -1.f;
    int bidx = 0;
#pragma unroll
    for (int jj = 0; jj < 8; ++jj) {
      const float pv = E[ii][jj] * ul[ii] * vl[jj];
      vals[jj] = pv;
      if (pv > best) {
        best = pv;
        bidx = j0 + jj;
      }
    }
    *reinterpret_cast<float4*>(&out[(i0 + ii) * 256 + j0]) =
        make_float4(vals[0], vals[1], vals[2], vals[3]);
    *reinterpret_cast<float4*>(&out[(i0 + ii) * 256 + j0 + 4]) =
        make_float4(vals[4], vals[5], vals[6], vals[7]);
    part[ty][ii][tx] = best;
    partI[ty][ii][tx] = bidx;
  }
  __syncthreads();
  if (tid < 256) {
    const int i = tid;
    float best = -1.f;
    int bidx = 1 << 30;
#pragma unroll
    for (int pp = 0; pp < 32; ++pp) {
      const int pr = (pp + i) & 31;
      const float v = part[i >> 3][i & 7][pr];
      const int ix = partI[i >> 3][i & 7][pr];
      if (v > best || (v == best && ix < bidx)) {
        best = v;
        bidx = ix;
      }
    }
    amax[i] = bidx;
  }
  __syncthreads();
#pragma unroll
  for (int ii = 0; ii < 8; ++ii) {
    const int am = amax[i0 + ii];
    float4 h0, h1;
    h0.x = (j0 + 0 == am) ? 1.f : 0.f;
    h0.y = (j0 + 1 == am) ? 1.f : 0.f;
    h0.z = (j0 + 2 == am) ? 1.f : 0.f;
    h0.w = (j0 + 3 == am) ? 1.f : 0.f;
    h1.x = (j0 + 4 == am) ? 1.f : 0.f;
    h1.y = (j0 + 5 == am) ? 1.f : 0.f;
    h1.z = (j0 + 6 == am) ? 1.f : 0.f;
    h1.w = (j0 + 7 == am) ? 1.f : 0.f;
    *reinterpret_cast<float4*>(&out[65536 + (i0 + ii) * 256 + j0]) = h0;
    *reinterpret_cast<float4*>(&out[65536 + (i0 + ii) * 256 + j0 + 4]) = h1;
  }
}

// ---------------- host-side launch ------------------------------------------
extern "C" void kernel_launch(void* const* d_in, const int* in_sizes, int n_in,
                              void* d_out, int out_size, void* d_ws,
                              size_t ws_size, hipStream_t stream) {
  (void)in_sizes;
  (void)n_in;
  (void)out_size;
  (void)ws_size;
  const float* in_x = (const float*)d_in[0];
  const float* emb_w = (const float*)d_in[1];
  const float* emb_b = (const float*)d_in[2];
  const float* pos_emb = (const float*)d_in[3];
  const float* cls_emb = (const float*)d_in[4];
  const float* ipw = (const float*)d_in[5];
  const float* ipb = (const float*)d_in[6];
  const float* aow = (const float*)d_in[7];
  const float* aob = (const float*)d_in[8];
  const float* fw1 = (const float*)d_in[9];
  const float* fb1 = (const float*)d_in[10];
  const float* fw2 = (const float*)d_in[11];
  const float* fb2 = (const float*)d_in[12];
  const float* ln1g = (const float*)d_in[13];
  const float* ln1b = (const float*)d_in[14];
  const float* ln2g = (const float*)d_in[15];
  const float* ln2b = (const float*)d_in[16];
  const float* out_w = (const float*)d_in[17];
  const float* out_b = (const float*)d_in[18];
  float* out = (float*)d_out;
  float* ws = (float*)d_ws;

  float* src = ws;               // 131584
  float* qkv = ws + 131584;      // 394752
  float* attnO = ws + 526336;    // 131584
  float* ffh = ws + 657920;      // 526336
  float* logits = ws + 1184256;  // 65536
  float* part = ws + 1249792;    // max 8*526336
  float* gparts = part;

  embed_kernel<<<dim3(S_), dim3(256), 0, stream>>>(in_x, emb_w, emb_b, pos_emb,
                                                   cls_emb, src);
  for (int l = 0; l < 4; ++l) {
    // qkv: M=257 N=1536 K=512, splitK8 (kslice 64, nt=2)
    gemm_mfma<true><<<dim3(24 * MB_ * 8), dim3(256), 0, stream>>>(
        src, ipw + (size_t)l * 1536 * 512, part, S_, 1536, 512, 64, 24,
        S_ * 1536);
    reduce_elem<<<dim3(386), dim3(256), 0, stream>>>(part, ipb + l * 1536, qkv,
                                                     S_ * 1536, 1536, 8, 0);
    attn_kernel<<<dim3(S_, 8), dim3(256), 0, stream>>>(qkv, attnO);
    // proj: N=512 K=512, splitK16 (kslice 32, nt=1)
    gemm_mfma<true><<<dim3(8 * MB_ * 16), dim3(256), 0, stream>>>(
        attnO, aow + (size_t)l * 512 * 512, part, S_, 512, 512, 32, 8,
        S_ * D_);
    reduce_ln<<<dim3(S_), dim3(256), 0, stream>>>(part, aob + l * 512, src,
                                                  ln1g + l * 512,
                                                  ln1b + l * 512, 16);
    // ff1: N=2048 K=512, splitK8 (kslice 64, nt=2)
    gemm_mfma<false><<<dim3(32 * MB_ * 8), dim3(256), 0, stream>>>(
        src, fw1 + (size_t)l * 512 * 2048, part, S_, 2048, 512, 64, 32,
        S_ * 2048);
    reduce_elem<<<dim3(514), dim3(256), 0, stream>>>(part, fb1 + l * 2048, ffh,
                                                     S_ * 2048, 2048, 8, 1);
    // ff2: N=512 K=2048, splitK16 (kslice 128, nt=4)
    gemm_mfma<false><<<dim3(8 * MB_ * 16), dim3(256), 0, stream>>>(
        ffh, fw2 + (size_t)l * 2048 * 512, part, S_, 512, 2048, 128, 8,
        S_ * D_);
    reduce_ln<<<dim3(S_), dim3(256), 0, stream>>>(part, fb2 + l * 512, src,
                                                  ln2g + l * 512,
                                                  ln2b + l * 512, 16);
  }
  gemv_kernel<<<dim3(64, 8), dim3(256), 0, stream>>>(src, out_w, gparts);
  logits_reduce_kernel<<<dim3(64), dim3(256), 0, stream>>>(gparts, out_b,
                                                           logits);
  sinkhorn_kernel<<<dim3(1), dim3(1024), 0, stream>>>(logits, out);
}